// Round 1
// baseline (661.524 us; speedup 1.0000x reference)
//
#include <hip/hip_runtime.h>
#include <hip/hip_bf16.h>
#include <math.h>

typedef __hip_bfloat16 bf16;

#define NDIM 256
#define NHEAD 8
#define NGRP 64
#define DHEAD 32
#define NB 32
#define NT 4096
#define NTG 1024

__device__ __forceinline__ float gelu_exact(float x) {
    return 0.5f * x * (1.0f + erff(x * 0.70710678118654752440f));
}
__device__ __forceinline__ float sigmoidf_(float x) {
    return 1.0f / (1.0f + __expf(-x));
}

// ---------------- transpose small weight matrices for coalesced col access ----
__global__ void k_transpose(const float* __restrict__ ipw,
                            const float* __restrict__ opw,
                            const float* __restrict__ twm,
                            const float* __restrict__ pw1,
                            float* __restrict__ wqT, float* __restrict__ opwT,
                            float* __restrict__ twT, float* __restrict__ pw1T) {
    int id = blockIdx.x * 256 + threadIdx.x;
    if (id < 65536) {
        int k = id >> 8, c = id & 255;
        wqT[id]  = ipw[c * 256 + k];        // wq rows 0..255
        opwT[id] = opw[c * 256 + k];
        twT[id]  = twm[c * 256 + k];
    } else {
        int id2 = id - 65536;
        if (id2 < 32768) {
            int k = id2 >> 7, m = id2 & 127;
            pw1T[id2] = pw1[m * 256 + k];   // (128,256) -> (256,128)
        }
    }
}

// ---------------- global_feat mean over TG: one wave per (b,c) row ------------
__global__ void k_gmean(const float* __restrict__ gf, float* __restrict__ gmean) {
    int blk = blockIdx.x;                 // b*256 + c
    int lane = threadIdx.x;               // 64
    const float4* row = reinterpret_cast<const float4*>(gf + (size_t)blk * NTG);
    float s = 0.f;
    #pragma unroll
    for (int i = 0; i < 4; ++i) {
        float4 v = row[lane + 64 * i];
        s += v.x + v.y + v.z + v.w;
    }
    #pragma unroll
    for (int off = 32; off >= 1; off >>= 1) s += __shfl_xor(s, off);
    if (lane == 0) gmean[blk] = s * (1.0f / 1024.0f);
}

// ---------------- qh = queries @ wq^T + bq  (batch-independent) ---------------
__global__ void k_qh(const float* __restrict__ queries, const float* __restrict__ wqT,
                     const float* __restrict__ ipb, float* __restrict__ qh) {
    __shared__ float qrow[256];
    int n = blockIdx.x, c = threadIdx.x;
    qrow[c] = queries[n * 256 + c];
    __syncthreads();
    float s = ipb[c];
    for (int k = 0; k < 256; ++k) s += qrow[k] * wqT[k * 256 + c];
    qh[n * 256 + c] = s;
}

// ---------------- meta gelu + heart_shift ------------------------------------
__global__ void k_metahs(const float* __restrict__ meta, const float* __restrict__ mw,
                         const float* __restrict__ mb, const float* __restrict__ gmean,
                         const float* __restrict__ sw, const float* __restrict__ sb,
                         float* __restrict__ metag, float* __restrict__ hshift) {
    int b = blockIdx.x, c = threadIdx.x;
    float s = mb[c];
    #pragma unroll
    for (int j = 0; j < 6; ++j) s += meta[b * 6 + j] * mw[c * 6 + j];
    metag[b * 256 + c] = gelu_exact(s);
    if (c < 3) {
        float t = sb[c];
        const float* gm = gmean + b * 256;
        for (int k = 0; k < 256; ++k) t += gm[k] * sw[c * 256 + k];
        hshift[b * 4 + c] = tanhf(t) * 0.3f;
    }
}

// ---------------- KV projection: (B*TG,256) @ (256,512) -> bf16 ---------------
__global__ __launch_bounds__(256) void k_kvproj(
        const float* __restrict__ gf, const float* __restrict__ ipw,
        const float* __restrict__ ipb, bf16* __restrict__ kvh) {
    __shared__ __align__(16) float la[32][68];
    __shared__ __align__(16) float lw[32][68];
    int tid = threadIdx.x;
    int n0 = blockIdx.x * 64;
    int t0 = blockIdx.y * 64;
    int b = blockIdx.z;
    float acc[4][4];
    #pragma unroll
    for (int i = 0; i < 4; ++i)
        #pragma unroll
        for (int j = 0; j < 4; ++j) acc[i][j] = 0.f;
    int ti0 = (tid >> 4) * 4;
    int nj0 = (tid & 15) * 4;
    int att = tid & 63, atc = tid >> 6;
    int wtc = tid & 31, wtn = tid >> 5;
    for (int c0 = 0; c0 < 256; c0 += 32) {
        #pragma unroll
        for (int r = 0; r < 8; ++r) {
            int cc = atc + r * 4;
            la[cc][att] = gf[(size_t)(b * 256 + c0 + cc) * NTG + t0 + att];
        }
        #pragma unroll
        for (int r = 0; r < 8; ++r) {
            int nn = wtn + r * 8;
            lw[wtc][nn] = ipw[(256 + n0 + nn) * 256 + c0 + wtc];
        }
        __syncthreads();
        #pragma unroll
        for (int cc = 0; cc < 32; ++cc) {
            float4 a = *reinterpret_cast<const float4*>(&la[cc][ti0]);
            float4 w = *reinterpret_cast<const float4*>(&lw[cc][nj0]);
            float av[4] = {a.x, a.y, a.z, a.w};
            float wv[4] = {w.x, w.y, w.z, w.w};
            #pragma unroll
            for (int i = 0; i < 4; ++i)
                #pragma unroll
                for (int j = 0; j < 4; ++j) acc[i][j] += av[i] * wv[j];
        }
        __syncthreads();
    }
    float bias[4];
    #pragma unroll
    for (int j = 0; j < 4; ++j) bias[j] = ipb[256 + n0 + nj0 + j];
    #pragma unroll
    for (int i = 0; i < 4; ++i) {
        int t = t0 + ti0 + i;
        bf16 o4[4];
        #pragma unroll
        for (int j = 0; j < 4; ++j) o4[j] = __float2bfloat16(acc[i][j] + bias[j]);
        bf16* out = kvh + ((size_t)(b * 1024 + t) * 512 + n0 + nj0);
        *reinterpret_cast<uint2*>(out) = *reinterpret_cast<uint2*>(o4);
    }
}

// ---------------- attention: one block per (h,b); 4 threads per query ---------
__global__ __launch_bounds__(256) void k_attn(
        const bf16* __restrict__ kvh, const float* __restrict__ qh,
        float* __restrict__ ctx) {
    __shared__ __align__(16) float ks[128][36];
    __shared__ __align__(16) float vs[128][36];
    int tid = threadIdx.x;
    int h = blockIdx.x, b = blockIdx.y;
    int n = tid >> 2, ko = tid & 3;
    float qreg[32];
    {
        const float4* qp = reinterpret_cast<const float4*>(qh + n * 256 + h * 32);
        #pragma unroll
        for (int d4 = 0; d4 < 8; ++d4) {
            float4 v = qp[d4];
            qreg[4 * d4 + 0] = v.x; qreg[4 * d4 + 1] = v.y;
            qreg[4 * d4 + 2] = v.z; qreg[4 * d4 + 3] = v.w;
        }
    }
    float acc[32];
    #pragma unroll
    for (int d = 0; d < 32; ++d) acc[d] = 0.f;
    float l = 0.f;
    int ldd = tid & 31, ldr = tid >> 5;
    const float scale = 0.17677669529663687f;  // 1/sqrt(32)
    for (int kc = 0; kc < 8; ++kc) {
        int k0 = kc * 128;
        #pragma unroll
        for (int r = 0; r < 16; ++r) {
            int kk = ldr + r * 8;
            const bf16* src = kvh + (size_t)(b * 1024 + k0 + kk) * 512;
            ks[kk][ldd] = __bfloat162float(src[h * 32 + ldd]);
            vs[kk][ldd] = __bfloat162float(src[256 + h * 32 + ldd]);
        }
        __syncthreads();
        for (int k2 = 0; k2 < 32; ++k2) {
            int kl = ko + k2 * 4;
            const float4* kp = reinterpret_cast<const float4*>(&ks[kl][0]);
            float s = 0.f;
            #pragma unroll
            for (int d4 = 0; d4 < 8; ++d4) {
                float4 v = kp[d4];
                s += qreg[4*d4+0] * v.x + qreg[4*d4+1] * v.y
                   + qreg[4*d4+2] * v.z + qreg[4*d4+3] * v.w;
            }
            float e = __expf(s * scale);
            l += e;
            const float4* vp = reinterpret_cast<const float4*>(&vs[kl][0]);
            #pragma unroll
            for (int d4 = 0; d4 < 8; ++d4) {
                float4 v = vp[d4];
                acc[4*d4+0] += e * v.x; acc[4*d4+1] += e * v.y;
                acc[4*d4+2] += e * v.z; acc[4*d4+3] += e * v.w;
            }
        }
        __syncthreads();
    }
    #pragma unroll
    for (int off = 1; off <= 2; off <<= 1) {
        l += __shfl_xor(l, off);
        #pragma unroll
        for (int d = 0; d < 32; ++d) acc[d] += __shfl_xor(acc[d], off);
    }
    if (ko == 0) {
        float inv = 1.0f / l;
        float* dst = ctx + (size_t)(b * 64 + n) * 256 + h * 32;
        #pragma unroll
        for (int d4 = 0; d4 < 8; ++d4) {
            float4 o;
            o.x = acc[4*d4+0] * inv; o.y = acc[4*d4+1] * inv;
            o.z = acc[4*d4+2] * inv; o.w = acc[4*d4+3] * inv;
            reinterpret_cast<float4*>(dst)[d4] = o;
        }
    }
}

// ---------------- out_proj + LN + meta + tw + phase MLP + geometry -----------
__global__ __launch_bounds__(256) void k_post(
        const float* __restrict__ ctx, const float* __restrict__ queries,
        const float* __restrict__ opwT, const float* __restrict__ opb,
        const float* __restrict__ lng, const float* __restrict__ lnb,
        const float* __restrict__ metag, const float* __restrict__ hshift,
        const float* __restrict__ twT, const float* __restrict__ tbv,
        const float* __restrict__ pw1T, const float* __restrict__ pb1,
        const float* __restrict__ pw2, const float* __restrict__ pb2,
        const float* __restrict__ p0a,
        float* __restrict__ tw_out, float* __restrict__ out_amp,
        float* __restrict__ out_ppos, float* __restrict__ out_dip,
        float* __restrict__ out_vol) {
    __shared__ float cs[8][256];
    __shared__ float xs[8][256];
    __shared__ float qs[8][256];
    __shared__ float h1[8][128];
    __shared__ float ps[8][10];
    int tid = threadIdx.x;
    int n0 = blockIdx.x * 8, b = blockIdx.y;
    #pragma unroll
    for (int r = 0; r < 8; ++r)
        cs[r][tid] = ctx[(size_t)(b * 64 + n0 + r) * 256 + tid];
    __syncthreads();
    {   // x = q + ctx @ opw^T + opb
        int c = tid;
        float a[8];
        #pragma unroll
        for (int nn = 0; nn < 8; ++nn) a[nn] = opb[c];
        for (int k = 0; k < 256; ++k) {
            float w = opwT[k * 256 + c];
            #pragma unroll
            for (int nn = 0; nn < 8; ++nn) a[nn] += cs[nn][k] * w;
        }
        #pragma unroll
        for (int nn = 0; nn < 8; ++nn)
            xs[nn][c] = queries[(n0 + nn) * 256 + c] + a[nn];
    }
    __syncthreads();
    {   // LayerNorm + meta gelu add
        int w = tid >> 6, lane = tid & 63;
        for (int i = 0; i < 2; ++i) {
            int nr = w + i * 4;
            float x0 = xs[nr][lane], x1 = xs[nr][lane + 64],
                  x2 = xs[nr][lane + 128], x3 = xs[nr][lane + 192];
            float s = x0 + x1 + x2 + x3;
            #pragma unroll
            for (int off = 32; off >= 1; off >>= 1) s += __shfl_xor(s, off);
            float mu = s * (1.0f / 256.0f);
            float e0 = x0 - mu, e1 = x1 - mu, e2 = x2 - mu, e3 = x3 - mu;
            float v = e0*e0 + e1*e1 + e2*e2 + e3*e3;
            #pragma unroll
            for (int off = 32; off >= 1; off >>= 1) v += __shfl_xor(v, off);
            float rstd = 1.0f / sqrtf(v * (1.0f / 256.0f) + 1e-5f);
            #pragma unroll
            for (int j = 0; j < 4; ++j) {
                int c = lane + 64 * j;
                float val = (xs[nr][c] - mu) * rstd * lng[c] + lnb[c] + metag[b * 256 + c];
                qs[nr][c] = val;
            }
        }
    }
    __syncthreads();
    {   // tw = q_static @ temporal_w^T + tb   -> global
        int c = tid;
        float a[8];
        #pragma unroll
        for (int nn = 0; nn < 8; ++nn) a[nn] = tbv[c];
        for (int k = 0; k < 256; ++k) {
            float w = twT[k * 256 + c];
            #pragma unroll
            for (int nn = 0; nn < 8; ++nn) a[nn] += qs[nn][k] * w;
        }
        #pragma unroll
        for (int nn = 0; nn < 8; ++nn)
            tw_out[(size_t)(b * 64 + n0 + nn) * 256 + c] = a[nn];
    }
    {   // h1 = gelu(q_static @ ph_w1^T + pb1)
        int m = tid & 127, g = tid >> 7;
        float a[4];
        #pragma unroll
        for (int q4 = 0; q4 < 4; ++q4) a[q4] = pb1[m];
        for (int k = 0; k < 256; ++k) {
            float w = pw1T[k * 128 + m];
            #pragma unroll
            for (int q4 = 0; q4 < 4; ++q4) a[q4] += qs[g * 4 + q4][k] * w;
        }
        #pragma unroll
        for (int q4 = 0; q4 < 4; ++q4) h1[g * 4 + q4][m] = gelu_exact(a[q4]);
    }
    __syncthreads();
    if (tid < 80) {   // params = h1 @ ph_w2^T + pb2
        int nr = tid / 10, j = tid % 10;
        float s = pb2[j];
        for (int m = 0; m < 128; ++m) s += h1[nr][m] * pw2[j * 128 + m];
        ps[nr][j] = s;
    }
    __syncthreads();
    if (tid < 8) {
        int nr = tid;
        int gn = b * 64 + n0 + nr;
        #pragma unroll
        for (int j = 0; j < 3; ++j) {
            float delta = tanhf(ps[nr][j]) * 0.2f;
            out_ppos[gn * 3 + j] = p0a[(n0 + nr) * 3 + j] + delta + hshift[b * 4 + j];
        }
        float d0 = ps[nr][3], d1 = ps[nr][4], d2 = ps[nr][5];
        float dn = fmaxf(sqrtf(d0 * d0 + d1 * d1 + d2 * d2), 1e-6f);
        out_dip[gn * 3 + 0] = d0 / dn;
        out_dip[gn * 3 + 1] = d1 / dn;
        out_dip[gn * 3 + 2] = d2 / dn;
        #pragma unroll
        for (int j = 0; j < 3; ++j)
            out_vol[gn * 3 + j] = sigmoidf_(ps[nr][6 + j]) * 0.5f + 0.001f;
        out_amp[gn] = sigmoidf_(ps[nr][9]) + 0.0001f;
    }
}

// ---------------- argmax amplitude -> delay ----------------------------------
__global__ void k_delay(const float* __restrict__ out_amp, const float* __restrict__ out_ppos,
                        const float* __restrict__ wds, float* __restrict__ delay) {
    int b = blockIdx.x, lane = threadIdx.x;
    float v = out_amp[b * 64 + lane];
    int idx = lane;
    #pragma unroll
    for (int off = 1; off < 64; off <<= 1) {
        float ov = __shfl_xor(v, off);
        int oi = __shfl_xor(idx, off);
        if (ov > v || (ov == v && oi < idx)) { v = ov; idx = oi; }
    }
    float px[3], sa[3];
    #pragma unroll
    for (int j = 0; j < 3; ++j) px[j] = out_ppos[(b * 64 + lane) * 3 + j];
    #pragma unroll
    for (int j = 0; j < 3; ++j) sa[j] = __shfl(px[j], idx);
    float dx = px[0] - sa[0], dy = px[1] - sa[1], dz = px[2] - sa[2];
    float dist = sqrtf(dx * dx + dy * dy + dz * dz);
    float sp = log1pf(expf(wds[0]));
    delay[b * 64 + lane] = fminf(fmaxf(sp * dist, 0.f), 0.1f);
}

// ---------------- temporal logits: tw(64,256) @ local_feat(256,T) /16 --------
__global__ __launch_bounds__(256) void k_temporal(
        const float* __restrict__ lf, const float* __restrict__ tw,
        float* __restrict__ logits) {
    __shared__ __align__(16) float tws[256 * 68];
    __shared__ __align__(16) float lfs[16 * 68];
    int tid = threadIdx.x;
    int t0 = blockIdx.x * 64, b = blockIdx.y;
    const float* twb = tw + (size_t)b * 64 * 256;
    for (int it = 0; it < 64; ++it) {
        // n = it, c = tid
        tws[tid * 68 + it] = twb[it * 256 + tid];
    }
    __syncthreads();
    float acc[4][4];
    #pragma unroll
    for (int i = 0; i < 4; ++i)
        #pragma unroll
        for (int j = 0; j < 4; ++j) acc[i][j] = 0.f;
    int tj = tid & 15, ti = tid >> 4;
    int ltt = tid & 63, ltc = tid >> 6;
    for (int ch = 0; ch < 16; ++ch) {
        int c0 = ch * 16;
        #pragma unroll
        for (int r = 0; r < 4; ++r) {
            int cc = ltc + r * 4;
            lfs[cc * 68 + ltt] = lf[((size_t)b * 256 + c0 + cc) * 4096 + t0 + ltt];
        }
        __syncthreads();
        #pragma unroll
        for (int cc = 0; cc < 16; ++cc) {
            float4 a = *reinterpret_cast<const float4*>(&tws[(c0 + cc) * 68 + tj * 4]);
            float4 bb = *reinterpret_cast<const float4*>(&lfs[cc * 68 + ti * 4]);
            float av[4] = {a.x, a.y, a.z, a.w};
            float bv[4] = {bb.x, bb.y, bb.z, bb.w};
            #pragma unroll
            for (int nn = 0; nn < 4; ++nn)
                #pragma unroll
                for (int tt = 0; tt < 4; ++tt) acc[nn][tt] += av[nn] * bv[tt];
        }
        __syncthreads();
    }
    #pragma unroll
    for (int nn = 0; nn < 4; ++nn) {
        int n = tj * 4 + nn;
        float4 o;
        o.x = acc[nn][0] * 0.0625f; o.y = acc[nn][1] * 0.0625f;
        o.z = acc[nn][2] * 0.0625f; o.w = acc[nn][3] * 0.0625f;
        *reinterpret_cast<float4*>(&logits[(size_t)(b * 64 + n) * 4096 + t0 + ti * 4]) = o;
    }
}

// ---------------- warped sampling + sigmoid envelope -------------------------
__global__ void k_envelope(const float* __restrict__ logits, const float* __restrict__ delay,
                           const float* __restrict__ ebp, float* __restrict__ env) {
    int blk = blockIdx.x;
    int bn = blk >> 2, seg = blk & 3;
    int tid = threadIdx.x;
    float dl = delay[bn];
    float eb = ebp[0];
    const float* gl = logits + (size_t)bn * 4096;
    int t_base = seg * 1024 + tid * 4;
    float ov[4];
    #pragma unroll
    for (int u = 0; u < 4; ++u) {
        int t = t_base + u;
        float xb = fmaf((float)t, 2.0f / 4095.0f, -1.0f);
        float xp = (xb - dl + 1.0f) * 2047.5f;
        float x0f = floorf(xp);
        int x0 = (int)x0f;
        float w1 = xp - x0f, w0 = 1.0f - w1;
        float g0 = (x0 >= 0 && x0 <= 4095) ? gl[x0] : 0.f;
        int x1 = x0 + 1;
        float g1 = (x1 >= 0 && x1 <= 4095) ? gl[x1] : 0.f;
        float sh = w0 * g0 + w1 * g1;
        ov[u] = 1.0f / (1.0f + __expf(-(sh + eb)));
    }
    float4 o; o.x = ov[0]; o.y = ov[1]; o.z = ov[2]; o.w = ov[3];
    *reinterpret_cast<float4*>(&env[(size_t)bn * 4096 + t_base]) = o;
}

extern "C" void kernel_launch(void* const* d_in, const int* in_sizes, int n_in,
                              void* d_out, int out_size, void* d_ws, size_t ws_size,
                              hipStream_t stream) {
    const float* lf   = (const float*)d_in[0];
    const float* gf   = (const float*)d_in[1];
    const float* meta = (const float*)d_in[2];
    const float* qrs  = (const float*)d_in[3];
    const float* p0a  = (const float*)d_in[4];
    const float* ipw  = (const float*)d_in[5];
    const float* ipb  = (const float*)d_in[6];
    const float* opw  = (const float*)d_in[7];
    const float* opb  = (const float*)d_in[8];
    const float* lng  = (const float*)d_in[9];
    const float* lnb  = (const float*)d_in[10];
    const float* mw   = (const float*)d_in[11];
    const float* mb   = (const float*)d_in[12];
    const float* twm  = (const float*)d_in[13];
    const float* tbv  = (const float*)d_in[14];
    const float* sw   = (const float*)d_in[15];
    const float* sb   = (const float*)d_in[16];
    const float* pw1  = (const float*)d_in[17];
    const float* pb1  = (const float*)d_in[18];
    const float* pw2  = (const float*)d_in[19];
    const float* pb2  = (const float*)d_in[20];
    const float* wds  = (const float*)d_in[21];
    const float* ebp  = (const float*)d_in[22];

    char* ws = (char*)d_ws;
    bf16*  kvh    = (bf16*)ws;                       // 33,554,432 B
    float* logits = (float*)(ws + 33554432);         // 33,554,432 B
    float* ctx    = (float*)(ws + 67108864);         //  2,097,152 B
    float* tw     = (float*)(ws + 69206016);         //  2,097,152 B
    float* qh     = (float*)(ws + 71303168);         //     65,536 B
    float* gmean  = (float*)(ws + 71368704);         //     32,768 B
    float* metag  = (float*)(ws + 71401472);         //     32,768 B
    float* hshift = (float*)(ws + 71434240);         //        512 B
    float* delay  = (float*)(ws + 71434752);         //      8,192 B
    float* opwT   = (float*)(ws + 71442944);         //    262,144 B
    float* twT    = (float*)(ws + 71705088);         //    262,144 B
    float* pw1T   = (float*)(ws + 71967232);         //    131,072 B
    float* wqT    = (float*)(ws + 72098304);         //    262,144 B

    float* out_amp  = (float*)d_out;
    float* out_ppos = out_amp + 2048;
    float* out_dip  = out_amp + 8192;
    float* out_vol  = out_amp + 14336;
    float* env      = out_amp + 20480;

    k_transpose<<<384, 256, 0, stream>>>(ipw, opw, twm, pw1, wqT, opwT, twT, pw1T);
    k_gmean<<<8192, 64, 0, stream>>>(gf, gmean);
    k_qh<<<64, 256, 0, stream>>>(qrs, wqT, ipb, qh);
    k_metahs<<<32, 256, 0, stream>>>(meta, mw, mb, gmean, sw, sb, metag, hshift);
    k_kvproj<<<dim3(8, 16, 32), 256, 0, stream>>>(gf, ipw, ipb, kvh);
    k_attn<<<dim3(8, 32), 256, 0, stream>>>(kvh, qh, ctx);
    k_post<<<dim3(8, 32), 256, 0, stream>>>(ctx, qrs, opwT, opb, lng, lnb, metag, hshift,
                                            twT, tbv, pw1T, pb1, pw2, pb2, p0a,
                                            tw, out_amp, out_ppos, out_dip, out_vol);
    k_delay<<<32, 64, 0, stream>>>(out_amp, out_ppos, wds, delay);
    k_temporal<<<dim3(64, 32), 256, 0, stream>>>(lf, tw, logits);
    k_envelope<<<8192, 256, 0, stream>>>(logits, delay, ebp, env);
}

// Round 2
// 492.237 us; speedup vs baseline: 1.3439x; 1.3439x over previous
//
#include <hip/hip_runtime.h>
#include <hip/hip_bf16.h>
#include <math.h>

typedef __hip_bfloat16 bf16;
typedef short s16x8 __attribute__((ext_vector_type(8)));
typedef float f32x4 __attribute__((ext_vector_type(4)));

#define NDIM 256
#define NTG 1024
#define NT 4096

__device__ __forceinline__ float gelu_exact(float x) {
    return 0.5f * x * (1.0f + erff(x * 0.70710678118654752440f));
}
__device__ __forceinline__ float sigmoidf_(float x) {
    return 1.0f / (1.0f + __expf(-x));
}
__device__ __forceinline__ short f2bf_s(float x) {
    union { bf16 h; short s; } cv;
    cv.h = __float2bfloat16(x);
    return cv.s;
}

// ---------------- transpose small weight matrices ----------------------------
__global__ void k_transpose(const float* __restrict__ ipw,
                            const float* __restrict__ opw,
                            const float* __restrict__ twm,
                            const float* __restrict__ pw1,
                            float* __restrict__ wqT, float* __restrict__ opwT,
                            float* __restrict__ twT, float* __restrict__ pw1T) {
    int id = blockIdx.x * 256 + threadIdx.x;
    if (id < 65536) {
        int k = id >> 8, c = id & 255;
        wqT[id]  = ipw[c * 256 + k];
        opwT[id] = opw[c * 256 + k];
        twT[id]  = twm[c * 256 + k];
    } else {
        int id2 = id - 65536;
        if (id2 < 32768) {
            int k = id2 >> 7, m = id2 & 127;
            pw1T[id2] = pw1[m * 256 + k];
        }
    }
}

// ---------------- convert KV weights to bf16 [n][c] --------------------------
__global__ void k_wcvt(const float* __restrict__ ipw, bf16* __restrict__ wkv) {
    int id = blockIdx.x * 256 + threadIdx.x;   // 131072
    wkv[id] = __float2bfloat16(ipw[65536 + id]);
}

// ---------------- transpose gf -> gfT_bf[b][t][c] bf16 -----------------------
__global__ __launch_bounds__(256) void k_gft(const float* __restrict__ gf,
                                             bf16* __restrict__ gfT) {
    __shared__ float tile[64][65];
    int tid = threadIdx.x;
    int t0 = blockIdx.x * 64, c0 = blockIdx.y * 64, b = blockIdx.z;
    int tt = tid & 63, ci = tid >> 6;
    #pragma unroll
    for (int r = 0; r < 16; ++r) {
        int cl = ci * 16 + r;
        tile[cl][tt] = gf[((size_t)(b * 256 + c0 + cl)) * NTG + t0 + tt];
    }
    __syncthreads();
    int cc = tid & 63, ti = tid >> 6;
    #pragma unroll
    for (int r = 0; r < 16; ++r) {
        int tl = ti * 16 + r;
        gfT[((size_t)(b * 1024 + t0 + tl)) * 256 + c0 + cc] =
            __float2bfloat16(tile[cc][tl]);
    }
}

// ---------------- global_feat mean -------------------------------------------
__global__ void k_gmean(const float* __restrict__ gf, float* __restrict__ gmean) {
    int blk = blockIdx.x;
    int lane = threadIdx.x;
    const float4* row = reinterpret_cast<const float4*>(gf + (size_t)blk * NTG);
    float s = 0.f;
    #pragma unroll
    for (int i = 0; i < 4; ++i) {
        float4 v = row[lane + 64 * i];
        s += v.x + v.y + v.z + v.w;
    }
    #pragma unroll
    for (int off = 32; off >= 1; off >>= 1) s += __shfl_xor(s, off);
    if (lane == 0) gmean[blk] = s * (1.0f / 1024.0f);
}

// ---------------- qh = queries @ wq^T + bq -----------------------------------
__global__ void k_qh(const float* __restrict__ queries, const float* __restrict__ wqT,
                     const float* __restrict__ ipb, float* __restrict__ qh) {
    __shared__ float qrow[256];
    int n = blockIdx.x, c = threadIdx.x;
    qrow[c] = queries[n * 256 + c];
    __syncthreads();
    float s = ipb[c];
    for (int k = 0; k < 256; ++k) s += qrow[k] * wqT[k * 256 + c];
    qh[n * 256 + c] = s;
}

// ---------------- meta gelu + heart_shift ------------------------------------
__global__ void k_metahs(const float* __restrict__ meta, const float* __restrict__ mw,
                         const float* __restrict__ mb, const float* __restrict__ gmean,
                         const float* __restrict__ sw, const float* __restrict__ sb,
                         float* __restrict__ metag, float* __restrict__ hshift) {
    int b = blockIdx.x, c = threadIdx.x;
    float s = mb[c];
    #pragma unroll
    for (int j = 0; j < 6; ++j) s += meta[b * 6 + j] * mw[c * 6 + j];
    metag[b * 256 + c] = gelu_exact(s);
    if (c < 3) {
        float t = sb[c];
        const float* gm = gmean + b * 256;
        for (int k = 0; k < 256; ++k) t += gm[k] * sw[c * 256 + k];
        hshift[b * 4 + c] = tanhf(t) * 0.3f;
    }
}

// ---------------- KV projection via MFMA bf16 --------------------------------
// D[t][n] = sum_c gfT[b][t][c] * wkv[n][c]  (+ ipb[256+n]) -> kvh bf16 [b][t][512]
__global__ __launch_bounds__(256) void k_kvproj(
        const bf16* __restrict__ gfT, const bf16* __restrict__ wkv,
        const float* __restrict__ ipb, bf16* __restrict__ kvh) {
    int tid = threadIdx.x;
    int wave = tid >> 6, lane = tid & 63;
    int lm = lane & 15, quad = lane >> 4;
    int m_base = blockIdx.x * 128 + wave * 32;
    int n_base = blockIdx.y * 64;
    int b = blockIdx.z;

    const short* A = (const short*)(gfT + ((size_t)b * 1024 + m_base) * 256);
    const short* B = (const short*)(wkv + (size_t)n_base * 256);

    f32x4 acc[2][4];
    #pragma unroll
    for (int mi = 0; mi < 2; ++mi)
        #pragma unroll
        for (int ni = 0; ni < 4; ++ni) acc[mi][ni] = (f32x4)(0.0f);

    #pragma unroll
    for (int ks = 0; ks < 8; ++ks) {
        int k0 = ks * 32 + quad * 8;
        s16x8 a0 = *(const s16x8*)(A + (lm)      * 256 + k0);
        s16x8 a1 = *(const s16x8*)(A + (lm + 16) * 256 + k0);
        #pragma unroll
        for (int ni = 0; ni < 4; ++ni) {
            s16x8 bf = *(const s16x8*)(B + (ni * 16 + lm) * 256 + k0);
            acc[0][ni] = __builtin_amdgcn_mfma_f32_16x16x32_bf16(a0, bf, acc[0][ni], 0, 0, 0);
            acc[1][ni] = __builtin_amdgcn_mfma_f32_16x16x32_bf16(a1, bf, acc[1][ni], 0, 0, 0);
        }
    }

    float bias[4];
    #pragma unroll
    for (int ni = 0; ni < 4; ++ni) bias[ni] = ipb[256 + n_base + ni * 16 + lm];

    #pragma unroll
    for (int mi = 0; mi < 2; ++mi) {
        #pragma unroll
        for (int ni = 0; ni < 4; ++ni) {
            int n = n_base + ni * 16 + lm;
            #pragma unroll
            for (int r = 0; r < 4; ++r) {
                int t = m_base + mi * 16 + quad * 4 + r;
                kvh[((size_t)b * 1024 + t) * 512 + n] =
                    __float2bfloat16(acc[mi][ni][r] + bias[ni]);
            }
        }
    }
}

// ---------------- attention split-K: grid (kc, h, b) -------------------------
__global__ __launch_bounds__(256) void k_attn(
        const bf16* __restrict__ kvh, const float* __restrict__ qh,
        float* __restrict__ pacc, float* __restrict__ pl) {
    __shared__ __align__(16) float ks[128][36];
    __shared__ __align__(16) float vs[128][36];
    int tid = threadIdx.x;
    int kc = blockIdx.x, h = blockIdx.y, b = blockIdx.z;
    int k0 = kc * 128;
    {
        int ldd = tid & 31, ldr = tid >> 5;
        #pragma unroll
        for (int r = 0; r < 16; ++r) {
            int kk = ldr + r * 8;
            const bf16* src = kvh + (size_t)(b * 1024 + k0 + kk) * 512;
            ks[kk][ldd] = __bfloat162float(src[h * 32 + ldd]);
            vs[kk][ldd] = __bfloat162float(src[256 + h * 32 + ldd]);
        }
    }
    __syncthreads();
    int qp = tid >> 3, kl = tid & 7;
    int q0 = qp * 2;
    float qr0[32], qr1[32];
    {
        const float4* p0 = reinterpret_cast<const float4*>(qh + q0 * 256 + h * 32);
        const float4* p1 = reinterpret_cast<const float4*>(qh + (q0 + 1) * 256 + h * 32);
        #pragma unroll
        for (int d4 = 0; d4 < 8; ++d4) {
            float4 v0 = p0[d4], v1 = p1[d4];
            qr0[4*d4+0]=v0.x; qr0[4*d4+1]=v0.y; qr0[4*d4+2]=v0.z; qr0[4*d4+3]=v0.w;
            qr1[4*d4+0]=v1.x; qr1[4*d4+1]=v1.y; qr1[4*d4+2]=v1.z; qr1[4*d4+3]=v1.w;
        }
    }
    float acc0[32], acc1[32];
    #pragma unroll
    for (int d = 0; d < 32; ++d) { acc0[d] = 0.f; acc1[d] = 0.f; }
    float l0 = 0.f, l1 = 0.f;
    const float scale = 0.17677669529663687f;
    for (int it = 0; it < 16; ++it) {
        int key = kl + it * 8;
        const float4* kp = reinterpret_cast<const float4*>(&ks[key][0]);
        float s0 = 0.f, s1 = 0.f;
        #pragma unroll
        for (int d4 = 0; d4 < 8; ++d4) {
            float4 v = kp[d4];
            s0 += qr0[4*d4+0]*v.x + qr0[4*d4+1]*v.y + qr0[4*d4+2]*v.z + qr0[4*d4+3]*v.w;
            s1 += qr1[4*d4+0]*v.x + qr1[4*d4+1]*v.y + qr1[4*d4+2]*v.z + qr1[4*d4+3]*v.w;
        }
        float e0 = __expf(s0 * scale), e1 = __expf(s1 * scale);
        l0 += e0; l1 += e1;
        const float4* vp = reinterpret_cast<const float4*>(&vs[key][0]);
        #pragma unroll
        for (int d4 = 0; d4 < 8; ++d4) {
            float4 v = vp[d4];
            acc0[4*d4+0]+=e0*v.x; acc0[4*d4+1]+=e0*v.y; acc0[4*d4+2]+=e0*v.z; acc0[4*d4+3]+=e0*v.w;
            acc1[4*d4+0]+=e1*v.x; acc1[4*d4+1]+=e1*v.y; acc1[4*d4+2]+=e1*v.z; acc1[4*d4+3]+=e1*v.w;
        }
    }
    #pragma unroll
    for (int off = 1; off <= 4; off <<= 1) {
        l0 += __shfl_xor(l0, off);
        l1 += __shfl_xor(l1, off);
        #pragma unroll
        for (int d = 0; d < 32; ++d) {
            acc0[d] += __shfl_xor(acc0[d], off);
            acc1[d] += __shfl_xor(acc1[d], off);
        }
    }
    if (kl == 0) {
        size_t row = ((size_t)(b * 8 + h) * 8 + kc) * 64 + q0;
        float* d0 = pacc + row * 32;
        float* d1 = pacc + (row + 1) * 32;
        #pragma unroll
        for (int d4 = 0; d4 < 8; ++d4) {
            float4 o0, o1;
            o0.x=acc0[4*d4+0]; o0.y=acc0[4*d4+1]; o0.z=acc0[4*d4+2]; o0.w=acc0[4*d4+3];
            o1.x=acc1[4*d4+0]; o1.y=acc1[4*d4+1]; o1.z=acc1[4*d4+2]; o1.w=acc1[4*d4+3];
            reinterpret_cast<float4*>(d0)[d4] = o0;
            reinterpret_cast<float4*>(d1)[d4] = o1;
        }
        pl[row] = l0; pl[row + 1] = l1;
    }
}

// ---------------- attention partial reduce -----------------------------------
__global__ void k_attn_reduce(const float* __restrict__ pacc, const float* __restrict__ pl,
                              float* __restrict__ ctx) {
    int bh = blockIdx.x;
    int b = bh >> 3, h = bh & 7;
    int tid = threadIdx.x;
    int q = tid >> 2, dg = tid & 3;
    size_t base = (size_t)bh * 512;
    float l = 0.f;
    float a[8];
    #pragma unroll
    for (int j = 0; j < 8; ++j) a[j] = 0.f;
    #pragma unroll
    for (int kcc = 0; kcc < 8; ++kcc) {
        size_t row = base + kcc * 64 + q;
        l += pl[row];
        const float* pa = pacc + row * 32 + dg * 8;
        #pragma unroll
        for (int j = 0; j < 8; ++j) a[j] += pa[j];
    }
    float inv = 1.0f / l;
    float* dst = ctx + (size_t)(b * 64 + q) * 256 + h * 32 + dg * 8;
    #pragma unroll
    for (int j = 0; j < 8; ++j) dst[j] = a[j] * inv;
}

// ---------------- out_proj + LN + meta + tw + phase MLP + geometry -----------
__global__ __launch_bounds__(256) void k_post(
        const float* __restrict__ ctx, const float* __restrict__ queries,
        const float* __restrict__ opwT, const float* __restrict__ opb,
        const float* __restrict__ lng, const float* __restrict__ lnb,
        const float* __restrict__ metag, const float* __restrict__ hshift,
        const float* __restrict__ twT, const float* __restrict__ tbv,
        const float* __restrict__ pw1T, const float* __restrict__ pb1,
        const float* __restrict__ pw2, const float* __restrict__ pb2,
        const float* __restrict__ p0a,
        float* __restrict__ tw_out, float* __restrict__ out_amp,
        float* __restrict__ out_ppos, float* __restrict__ out_dip,
        float* __restrict__ out_vol) {
    __shared__ float cs[8][256];
    __shared__ float xs[8][256];
    __shared__ float qs[8][256];
    __shared__ float h1[8][128];
    __shared__ float ps[8][10];
    int tid = threadIdx.x;
    int n0 = blockIdx.x * 8, b = blockIdx.y;
    #pragma unroll
    for (int r = 0; r < 8; ++r)
        cs[r][tid] = ctx[(size_t)(b * 64 + n0 + r) * 256 + tid];
    __syncthreads();
    {
        int c = tid;
        float a[8];
        #pragma unroll
        for (int nn = 0; nn < 8; ++nn) a[nn] = opb[c];
        for (int k = 0; k < 256; ++k) {
            float w = opwT[k * 256 + c];
            #pragma unroll
            for (int nn = 0; nn < 8; ++nn) a[nn] += cs[nn][k] * w;
        }
        #pragma unroll
        for (int nn = 0; nn < 8; ++nn)
            xs[nn][c] = queries[(n0 + nn) * 256 + c] + a[nn];
    }
    __syncthreads();
    {
        int w = tid >> 6, lane = tid & 63;
        for (int i = 0; i < 2; ++i) {
            int nr = w + i * 4;
            float x0 = xs[nr][lane], x1 = xs[nr][lane + 64],
                  x2 = xs[nr][lane + 128], x3 = xs[nr][lane + 192];
            float s = x0 + x1 + x2 + x3;
            #pragma unroll
            for (int off = 32; off >= 1; off >>= 1) s += __shfl_xor(s, off);
            float mu = s * (1.0f / 256.0f);
            float e0 = x0 - mu, e1 = x1 - mu, e2 = x2 - mu, e3 = x3 - mu;
            float v = e0*e0 + e1*e1 + e2*e2 + e3*e3;
            #pragma unroll
            for (int off = 32; off >= 1; off >>= 1) v += __shfl_xor(v, off);
            float rstd = 1.0f / sqrtf(v * (1.0f / 256.0f) + 1e-5f);
            #pragma unroll
            for (int j = 0; j < 4; ++j) {
                int c = lane + 64 * j;
                qs[nr][c] = (xs[nr][c] - mu) * rstd * lng[c] + lnb[c] + metag[b * 256 + c];
            }
        }
    }
    __syncthreads();
    {
        int c = tid;
        float a[8];
        #pragma unroll
        for (int nn = 0; nn < 8; ++nn) a[nn] = tbv[c];
        for (int k = 0; k < 256; ++k) {
            float w = twT[k * 256 + c];
            #pragma unroll
            for (int nn = 0; nn < 8; ++nn) a[nn] += qs[nn][k] * w;
        }
        #pragma unroll
        for (int nn = 0; nn < 8; ++nn)
            tw_out[(size_t)(b * 64 + n0 + nn) * 256 + c] = a[nn];
    }
    {
        int m = tid & 127, g = tid >> 7;
        float a[4];
        #pragma unroll
        for (int q4 = 0; q4 < 4; ++q4) a[q4] = pb1[m];
        for (int k = 0; k < 256; ++k) {
            float w = pw1T[k * 128 + m];
            #pragma unroll
            for (int q4 = 0; q4 < 4; ++q4) a[q4] += qs[g * 4 + q4][k] * w;
        }
        #pragma unroll
        for (int q4 = 0; q4 < 4; ++q4) h1[g * 4 + q4][m] = gelu_exact(a[q4]);
    }
    __syncthreads();
    if (tid < 80) {
        int nr = tid / 10, j = tid % 10;
        float s = pb2[j];
        for (int m = 0; m < 128; ++m) s += h1[nr][m] * pw2[j * 128 + m];
        ps[nr][j] = s;
    }
    __syncthreads();
    if (tid < 8) {
        int nr = tid;
        int gn = b * 64 + n0 + nr;
        #pragma unroll
        for (int j = 0; j < 3; ++j) {
            float delta = tanhf(ps[nr][j]) * 0.2f;
            out_ppos[gn * 3 + j] = p0a[(n0 + nr) * 3 + j] + delta + hshift[b * 4 + j];
        }
        float d0 = ps[nr][3], d1 = ps[nr][4], d2 = ps[nr][5];
        float dn = fmaxf(sqrtf(d0 * d0 + d1 * d1 + d2 * d2), 1e-6f);
        out_dip[gn * 3 + 0] = d0 / dn;
        out_dip[gn * 3 + 1] = d1 / dn;
        out_dip[gn * 3 + 2] = d2 / dn;
        #pragma unroll
        for (int j = 0; j < 3; ++j)
            out_vol[gn * 3 + j] = sigmoidf_(ps[nr][6 + j]) * 0.5f + 0.001f;
        out_amp[gn] = sigmoidf_(ps[nr][9]) + 0.0001f;
    }
}

// ---------------- argmax amplitude -> delay ----------------------------------
__global__ void k_delay(const float* __restrict__ out_amp, const float* __restrict__ out_ppos,
                        const float* __restrict__ wds, float* __restrict__ delay) {
    int b = blockIdx.x, lane = threadIdx.x;
    float v = out_amp[b * 64 + lane];
    int idx = lane;
    #pragma unroll
    for (int off = 1; off < 64; off <<= 1) {
        float ov = __shfl_xor(v, off);
        int oi = __shfl_xor(idx, off);
        if (ov > v || (ov == v && oi < idx)) { v = ov; idx = oi; }
    }
    float px[3], sa[3];
    #pragma unroll
    for (int j = 0; j < 3; ++j) px[j] = out_ppos[(b * 64 + lane) * 3 + j];
    #pragma unroll
    for (int j = 0; j < 3; ++j) sa[j] = __shfl(px[j], idx);
    float dx = px[0] - sa[0], dy = px[1] - sa[1], dz = px[2] - sa[2];
    float dist = sqrtf(dx * dx + dy * dy + dz * dz);
    float sp = log1pf(expf(wds[0]));
    delay[b * 64 + lane] = fminf(fmaxf(sp * dist, 0.f), 0.1f);
}

// ---------------- temporal logits via MFMA bf16 ------------------------------
// logits[b][n][t] = sum_c tw[b][n][c] * lf[b][c][t] / 16
__global__ __launch_bounds__(256) void k_temporal(
        const float* __restrict__ lf, const float* __restrict__ tw,
        float* __restrict__ logits) {
    __shared__ __align__(16) float lfs[32 * 132];
    __shared__ __align__(16) short tws[64 * 264];
    int tid = threadIdx.x;
    int t0 = blockIdx.x * 128, b = blockIdx.y;
    int wave = tid >> 6, lane = tid & 63;
    int lm = lane & 15, quad = lane >> 4;

    // stage tw (64x256) -> bf16 LDS
    const float* twb = tw + (size_t)b * 64 * 256;
    #pragma unroll
    for (int i = 0; i < 64; ++i) {
        tws[i * 264 + tid] = f2bf_s(twb[i * 256 + tid]);
    }

    f32x4 acc[2][4];
    #pragma unroll
    for (int mi = 0; mi < 2; ++mi)
        #pragma unroll
        for (int ni = 0; ni < 4; ++ni) acc[mi][ni] = (f32x4)(0.0f);

    for (int ksi = 0; ksi < 8; ++ksi) {
        int c0 = ksi * 32;
        // stage lf chunk: 32 c-rows x 128 t, fp32
        #pragma unroll
        for (int r = 0; r < 4; ++r) {
            int fi = r * 256 + tid;
            int c = fi >> 5, t4 = fi & 31;
            *reinterpret_cast<float4*>(&lfs[c * 132 + t4 * 4]) =
                *reinterpret_cast<const float4*>(
                    &lf[((size_t)b * 256 + c0 + c) * 4096 + t0 + t4 * 4]);
        }
        __syncthreads();
        #pragma unroll
        for (int mi = 0; mi < 2; ++mi) {
            int ml = wave * 32 + mi * 16 + lm;
            s16x8 af;
            #pragma unroll
            for (int j = 0; j < 8; ++j)
                af[j] = f2bf_s(lfs[(quad * 8 + j) * 132 + ml]);
            #pragma unroll
            for (int ni = 0; ni < 4; ++ni) {
                s16x8 bfr = *reinterpret_cast<const s16x8*>(
                    &tws[(ni * 16 + lm) * 264 + c0 + quad * 8]);
                acc[mi][ni] = __builtin_amdgcn_mfma_f32_16x16x32_bf16(af, bfr, acc[mi][ni], 0, 0, 0);
            }
        }
        __syncthreads();
    }
    #pragma unroll
    for (int mi = 0; mi < 2; ++mi) {
        #pragma unroll
        for (int ni = 0; ni < 4; ++ni) {
            int n = ni * 16 + lm;
            int t = t0 + wave * 32 + mi * 16 + quad * 4;
            float4 o;
            o.x = acc[mi][ni][0] * 0.0625f;
            o.y = acc[mi][ni][1] * 0.0625f;
            o.z = acc[mi][ni][2] * 0.0625f;
            o.w = acc[mi][ni][3] * 0.0625f;
            *reinterpret_cast<float4*>(&logits[(size_t)(b * 64 + n) * 4096 + t]) = o;
        }
    }
}

// ---------------- warped sampling + sigmoid envelope -------------------------
__global__ void k_envelope(const float* __restrict__ logits, const float* __restrict__ delay,
                           const float* __restrict__ ebp, float* __restrict__ env) {
    int blk = blockIdx.x;
    int bn = blk >> 2, seg = blk & 3;
    int tid = threadIdx.x;
    float dl = delay[bn];
    float eb = ebp[0];
    const float* gl = logits + (size_t)bn * 4096;
    int t_base = seg * 1024 + tid * 4;
    float ov[4];
    #pragma unroll
    for (int u = 0; u < 4; ++u) {
        int t = t_base + u;
        float xb = fmaf((float)t, 2.0f / 4095.0f, -1.0f);
        float xp = (xb - dl + 1.0f) * 2047.5f;
        float x0f = floorf(xp);
        int x0 = (int)x0f;
        float w1 = xp - x0f, w0 = 1.0f - w1;
        float g0 = (x0 >= 0 && x0 <= 4095) ? gl[x0] : 0.f;
        int x1 = x0 + 1;
        float g1 = (x1 >= 0 && x1 <= 4095) ? gl[x1] : 0.f;
        float sh = w0 * g0 + w1 * g1;
        ov[u] = 1.0f / (1.0f + __expf(-(sh + eb)));
    }
    float4 o; o.x = ov[0]; o.y = ov[1]; o.z = ov[2]; o.w = ov[3];
    *reinterpret_cast<float4*>(&env[(size_t)bn * 4096 + t_base]) = o;
}

extern "C" void kernel_launch(void* const* d_in, const int* in_sizes, int n_in,
                              void* d_out, int out_size, void* d_ws, size_t ws_size,
                              hipStream_t stream) {
    const float* lf   = (const float*)d_in[0];
    const float* gf   = (const float*)d_in[1];
    const float* meta = (const float*)d_in[2];
    const float* qrs  = (const float*)d_in[3];
    const float* p0a  = (const float*)d_in[4];
    const float* ipw  = (const float*)d_in[5];
    const float* ipb  = (const float*)d_in[6];
    const float* opw  = (const float*)d_in[7];
    const float* opb  = (const float*)d_in[8];
    const float* lng  = (const float*)d_in[9];
    const float* lnb  = (const float*)d_in[10];
    const float* mw   = (const float*)d_in[11];
    const float* mb   = (const float*)d_in[12];
    const float* twm  = (const float*)d_in[13];
    const float* tbv  = (const float*)d_in[14];
    const float* sw   = (const float*)d_in[15];
    const float* sb   = (const float*)d_in[16];
    const float* pw1  = (const float*)d_in[17];
    const float* pb1  = (const float*)d_in[18];
    const float* pw2  = (const float*)d_in[19];
    const float* pb2  = (const float*)d_in[20];
    const float* wds  = (const float*)d_in[21];
    const float* ebp  = (const float*)d_in[22];

    char* ws = (char*)d_ws;
    // Region A: kvh bf16 [32][1024][512]            = 33,554,432 B
    bf16*  kvh    = (bf16*)ws;
    // Region R (33.5 MB), time-multiplexed:
    //   phase 1: gfT_bf (16,777,216 B)   [k_gft -> k_kvproj]
    //   phase 2: pacc (16,777,216) + pl (524,288)  [k_attn -> k_attn_reduce]
    //   phase 3: logits (33,554,432)     [k_temporal -> k_envelope]
    char*  R      = ws + 33554432;
    bf16*  gfT    = (bf16*)R;
    float* pacc   = (float*)R;
    float* pl     = (float*)(R + 16777216);
    float* logits = (float*)R;
    float* ctx    = (float*)(ws + 67108864);         //  2,097,152 B
    float* tw     = (float*)(ws + 69206016);         //  2,097,152 B
    float* qh     = (float*)(ws + 71303168);         //     65,536 B
    float* gmean  = (float*)(ws + 71368704);         //     32,768 B
    float* metag  = (float*)(ws + 71401472);         //     32,768 B
    float* hshift = (float*)(ws + 71434240);         //        512 B
    float* delay  = (float*)(ws + 71434752);         //      8,192 B
    float* opwT   = (float*)(ws + 71442944);         //    262,144 B
    float* twT    = (float*)(ws + 71705088);         //    262,144 B
    float* pw1T   = (float*)(ws + 71967232);         //    131,072 B
    float* wqT    = (float*)(ws + 72098304);         //    262,144 B
    bf16*  wkv    = (bf16*)(ws + 72360448);          //    262,144 B

    float* out_amp  = (float*)d_out;
    float* out_ppos = out_amp + 2048;
    float* out_dip  = out_amp + 8192;
    float* out_vol  = out_amp + 14336;
    float* env      = out_amp + 20480;

    k_transpose<<<384, 256, 0, stream>>>(ipw, opw, twm, pw1, wqT, opwT, twT, pw1T);
    k_wcvt<<<512, 256, 0, stream>>>(ipw, wkv);
    k_gft<<<dim3(16, 4, 32), 256, 0, stream>>>(gf, gfT);
    k_gmean<<<8192, 64, 0, stream>>>(gf, gmean);
    k_qh<<<64, 256, 0, stream>>>(qrs, wqT, ipb, qh);
    k_metahs<<<32, 256, 0, stream>>>(meta, mw, mb, gmean, sw, sb, metag, hshift);
    k_kvproj<<<dim3(8, 8, 32), 256, 0, stream>>>(gfT, wkv, ipb, kvh);
    k_attn<<<dim3(8, 8, 32), 256, 0, stream>>>(kvh, qh, pacc, pl);
    k_attn_reduce<<<256, 256, 0, stream>>>(pacc, pl, ctx);
    k_post<<<dim3(8, 32), 256, 0, stream>>>(ctx, qrs, opwT, opb, lng, lnb, metag, hshift,
                                            twT, tbv, pw1T, pb1, pw2, pb2, p0a,
                                            tw, out_amp, out_ppos, out_dip, out_vol);
    k_delay<<<32, 64, 0, stream>>>(out_amp, out_ppos, wds, delay);
    k_temporal<<<dim3(32, 32), 256, 0, stream>>>(lf, tw, logits);
    k_envelope<<<8192, 256, 0, stream>>>(logits, delay, ebp, env);
}

// Round 4
// 441.509 us; speedup vs baseline: 1.4983x; 1.1149x over previous
//
#include <hip/hip_runtime.h>
#include <hip/hip_bf16.h>
#include <math.h>

typedef __hip_bfloat16 bf16;
typedef short s16x8 __attribute__((ext_vector_type(8)));
typedef float f32x4 __attribute__((ext_vector_type(4)));

#define NDIM 256
#define NTG 1024
#define NT 4096

__device__ __forceinline__ float gelu_exact(float x) {
    return 0.5f * x * (1.0f + erff(x * 0.70710678118654752440f));
}
__device__ __forceinline__ float sigmoidf_(float x) {
    return 1.0f / (1.0f + __expf(-x));
}
__device__ __forceinline__ short f2bf_s(float x) {
    union { bf16 h; short s; } cv;
    cv.h = __float2bfloat16(x);
    return cv.s;
}

// ---------------- transpose small weight matrices ----------------------------
__global__ void k_transpose(const float* __restrict__ ipw,
                            const float* __restrict__ opw,
                            const float* __restrict__ twm,
                            const float* __restrict__ pw1,
                            float* __restrict__ wqT, float* __restrict__ opwT,
                            float* __restrict__ twT, float* __restrict__ pw1T) {
    int id = blockIdx.x * 256 + threadIdx.x;
    if (id < 65536) {
        int k = id >> 8, c = id & 255;
        wqT[id]  = ipw[c * 256 + k];
        opwT[id] = opw[c * 256 + k];
        twT[id]  = twm[c * 256 + k];
    } else {
        int id2 = id - 65536;
        if (id2 < 32768) {
            int k = id2 >> 7, m = id2 & 127;
            pw1T[id2] = pw1[m * 256 + k];
        }
    }
}

// ---------------- convert K/V weights to bf16 [n][c] -------------------------
__global__ void k_wcvt(const float* __restrict__ ipw,
                       bf16* __restrict__ wkvK, bf16* __restrict__ wkvV) {
    int id = blockIdx.x * 256 + threadIdx.x;   // 65536
    wkvK[id] = __float2bfloat16(ipw[65536 + id]);
    wkvV[id] = __float2bfloat16(ipw[131072 + id]);
}

// ---------------- transpose gf -> gfT_bf[b][t][c] bf16 -----------------------
__global__ __launch_bounds__(256) void k_gft(const float* __restrict__ gf,
                                             bf16* __restrict__ gfT) {
    __shared__ float tile[64][65];
    int tid = threadIdx.x;
    int t0 = blockIdx.x * 64, c0 = blockIdx.y * 64, b = blockIdx.z;
    int tt = tid & 63, ci = tid >> 6;
    #pragma unroll
    for (int r = 0; r < 16; ++r) {
        int cl = ci * 16 + r;
        tile[cl][tt] = gf[((size_t)(b * 256 + c0 + cl)) * NTG + t0 + tt];
    }
    __syncthreads();
    int cc = tid & 63, ti = tid >> 6;
    #pragma unroll
    for (int r = 0; r < 16; ++r) {
        int tl = ti * 16 + r;
        gfT[((size_t)(b * 1024 + t0 + tl)) * 256 + c0 + cc] =
            __float2bfloat16(tile[cc][tl]);
    }
}

// ---------------- global_feat mean -------------------------------------------
__global__ void k_gmean(const float* __restrict__ gf, float* __restrict__ gmean) {
    int blk = blockIdx.x;
    int lane = threadIdx.x;
    const float4* row = reinterpret_cast<const float4*>(gf + (size_t)blk * NTG);
    float s = 0.f;
    #pragma unroll
    for (int i = 0; i < 4; ++i) {
        float4 v = row[lane + 64 * i];
        s += v.x + v.y + v.z + v.w;
    }
    #pragma unroll
    for (int off = 32; off >= 1; off >>= 1) s += __shfl_xor(s, off);
    if (lane == 0) gmean[blk] = s * (1.0f / 1024.0f);
}

// ---------------- qh = queries @ wq^T + bq -----------------------------------
__global__ void k_qh(const float* __restrict__ queries, const float* __restrict__ wqT,
                     const float* __restrict__ ipb, float* __restrict__ qh) {
    __shared__ float qrow[256];
    int n = blockIdx.x, c = threadIdx.x;
    qrow[c] = queries[n * 256 + c];
    __syncthreads();
    float s = ipb[c];
    for (int k = 0; k < 256; ++k) s += qrow[k] * wqT[k * 256 + c];
    qh[n * 256 + c] = s;
}

// ---------------- meta gelu + heart_shift ------------------------------------
__global__ void k_metahs(const float* __restrict__ meta, const float* __restrict__ mw,
                         const float* __restrict__ mb, const float* __restrict__ gmean,
                         const float* __restrict__ sw, const float* __restrict__ sb,
                         float* __restrict__ metag, float* __restrict__ hshift) {
    int b = blockIdx.x, c = threadIdx.x;
    float s = mb[c];
    #pragma unroll
    for (int j = 0; j < 6; ++j) s += meta[b * 6 + j] * mw[c * 6 + j];
    metag[b * 256 + c] = gelu_exact(s);
    if (c < 3) {
        float t = sb[c];
        const float* gm = gmean + b * 256;
        for (int k = 0; k < 256; ++k) t += gm[k] * sw[c * 256 + k];
        hshift[b * 4 + c] = tanhf(t) * 0.3f;
    }
}

// ---------------- K projection: kvh[b][t][256] = gfT @ wk^T + bk (bf16) ------
__global__ __launch_bounds__(256) void k_kproj(
        const short* __restrict__ gfT, const short* __restrict__ wkvK,
        const float* __restrict__ ipb, short* __restrict__ kvh) {
    int tid = threadIdx.x;
    int w = tid >> 6, lane = tid & 63, lm = lane & 15, quad = lane >> 4;
    int t0 = blockIdx.x * 128 + w * 32;
    int n0 = blockIdx.y * 64;
    int b = blockIdx.z;
    f32x4 acc[4][2];
    #pragma unroll
    for (int ni = 0; ni < 4; ++ni)
        #pragma unroll
        for (int mt = 0; mt < 2; ++mt) acc[ni][mt] = (f32x4)(0.0f);
    #pragma unroll
    for (int ks = 0; ks < 8; ++ks) {
        int c = ks * 32 + quad * 8;
        s16x8 bg[2];
        #pragma unroll
        for (int mt = 0; mt < 2; ++mt)
            bg[mt] = *(const s16x8*)&gfT[((size_t)(b * 1024 + t0 + mt * 16 + lm)) * 256 + c];
        #pragma unroll
        for (int ni = 0; ni < 4; ++ni) {
            s16x8 aw = *(const s16x8*)&wkvK[(n0 + ni * 16 + lm) * 256 + c];
            #pragma unroll
            for (int mt = 0; mt < 2; ++mt)
                acc[ni][mt] = __builtin_amdgcn_mfma_f32_16x16x32_bf16(aw, bg[mt], acc[ni][mt], 0, 0, 0);
        }
    }
    #pragma unroll
    for (int ni = 0; ni < 4; ++ni) {
        int nb4 = n0 + ni * 16 + quad * 4;
        float4 bias = *(const float4*)&ipb[256 + nb4];
        #pragma unroll
        for (int mt = 0; mt < 2; ++mt) {
            int t = t0 + mt * 16 + lm;
            ushort4 o;
            o.x = (unsigned short)f2bf_s(acc[ni][mt][0] + bias.x);
            o.y = (unsigned short)f2bf_s(acc[ni][mt][1] + bias.y);
            o.z = (unsigned short)f2bf_s(acc[ni][mt][2] + bias.z);
            o.w = (unsigned short)f2bf_s(acc[ni][mt][3] + bias.w);
            *(ushort4*)&kvh[((size_t)(b * 1024 + t)) * 256 + nb4] = o;
        }
    }
}

// ---------------- V projection: vTg[b][n][1024 t] = (gfT @ wv^T + bv)^T ------
__global__ __launch_bounds__(256) void k_vproj(
        const short* __restrict__ gfT, const short* __restrict__ wkvV,
        const float* __restrict__ ipb, short* __restrict__ vTg) {
    int tid = threadIdx.x;
    int w = tid >> 6, lane = tid & 63, lm = lane & 15, quad = lane >> 4;
    int t0 = blockIdx.x * 128 + w * 32;
    int n0 = blockIdx.y * 64;
    int b = blockIdx.z;
    f32x4 acc[2][4];
    #pragma unroll
    for (int mt = 0; mt < 2; ++mt)
        #pragma unroll
        for (int ni = 0; ni < 4; ++ni) acc[mt][ni] = (f32x4)(0.0f);
    #pragma unroll
    for (int ks = 0; ks < 8; ++ks) {
        int c = ks * 32 + quad * 8;
        s16x8 ag[2];
        #pragma unroll
        for (int mt = 0; mt < 2; ++mt)
            ag[mt] = *(const s16x8*)&gfT[((size_t)(b * 1024 + t0 + mt * 16 + lm)) * 256 + c];
        #pragma unroll
        for (int ni = 0; ni < 4; ++ni) {
            s16x8 bw = *(const s16x8*)&wkvV[(n0 + ni * 16 + lm) * 256 + c];
            #pragma unroll
            for (int mt = 0; mt < 2; ++mt)
                acc[mt][ni] = __builtin_amdgcn_mfma_f32_16x16x32_bf16(ag[mt], bw, acc[mt][ni], 0, 0, 0);
        }
    }
    #pragma unroll
    for (int ni = 0; ni < 4; ++ni) {
        int nv = n0 + ni * 16 + lm;
        float bias = ipb[512 + nv];
        #pragma unroll
        for (int mt = 0; mt < 2; ++mt) {
            int t4 = t0 + mt * 16 + quad * 4;
            ushort4 o;
            o.x = (unsigned short)f2bf_s(acc[mt][ni][0] + bias);
            o.y = (unsigned short)f2bf_s(acc[mt][ni][1] + bias);
            o.z = (unsigned short)f2bf_s(acc[mt][ni][2] + bias);
            o.w = (unsigned short)f2bf_s(acc[mt][ni][3] + bias);
            *(ushort4*)&vTg[((size_t)(b * 256 + nv)) * 1024 + t4] = o;
        }
    }
}

// ---------------- MFMA attention: grid (half, h, b), 4 waves x 128 keys ------
__global__ __launch_bounds__(256) void k_attn(
        const short* __restrict__ kvh, const short* __restrict__ vTg,
        const float* __restrict__ qh,
        float* __restrict__ o_half, float* __restrict__ l_half) {
    __shared__ short pT[4][64 * 40];
    __shared__ float obuf[4][64 * 36];
    __shared__ float lbuf[4 * 64];
    int tid = threadIdx.x;
    int w = tid >> 6, lane = tid & 63, lm = lane & 15, quad = lane >> 4;
    int half = blockIdx.x, h = blockIdx.y, b = blockIdx.z;
    s16x8 aq[4];
    #pragma unroll
    for (int mt = 0; mt < 4; ++mt) {
        const float* qp = qh + (mt * 16 + lm) * 256 + h * 32 + quad * 8;
        #pragma unroll
        for (int j = 0; j < 8; ++j) aq[mt][j] = f2bf_s(qp[j]);
    }
    f32x4 acco[2][4];
    #pragma unroll
    for (int dt = 0; dt < 2; ++dt)
        #pragma unroll
        for (int qt = 0; qt < 4; ++qt) acco[dt][qt] = (f32x4)(0.0f);
    float lp[4][4];
    #pragma unroll
    for (int mt = 0; mt < 4; ++mt)
        #pragma unroll
        for (int r = 0; r < 4; ++r) lp[mt][r] = 0.f;
    const float scale = 0.17677669529663687f;   // 1/sqrt(32)
    int kb = half * 512 + w * 128;
    for (int ch = 0; ch < 4; ++ch) {
        int n0 = kb + ch * 32;
        #pragma unroll
        for (int nt = 0; nt < 2; ++nt) {
            int key = n0 + nt * 16 + lm;
            s16x8 bk = *(const s16x8*)&kvh[((size_t)(b * 1024 + key)) * 256 + h * 32 + quad * 8];
            f32x4 zero = {0.f, 0.f, 0.f, 0.f};
            #pragma unroll
            for (int mt = 0; mt < 4; ++mt) {
                f32x4 S = __builtin_amdgcn_mfma_f32_16x16x32_bf16(aq[mt], bk, zero, 0, 0, 0);
                #pragma unroll
                for (int r = 0; r < 4; ++r) {
                    float e = __expf(S[r] * scale);
                    lp[mt][r] += e;
                    pT[w][(mt * 16 + quad * 4 + r) * 40 + nt * 16 + lm] = f2bf_s(e);
                }
            }
        }
        s16x8 av[2], bp[4];
        #pragma unroll
        for (int dt = 0; dt < 2; ++dt)
            av[dt] = *(const s16x8*)&vTg[((size_t)(b * 256 + h * 32 + dt * 16 + lm)) * 1024 + n0 + quad * 8];
        #pragma unroll
        for (int qt = 0; qt < 4; ++qt)
            bp[qt] = *(const s16x8*)&pT[w][(qt * 16 + lm) * 40 + quad * 8];
        #pragma unroll
        for (int dt = 0; dt < 2; ++dt)
            #pragma unroll
            for (int qt = 0; qt < 4; ++qt)
                acco[dt][qt] = __builtin_amdgcn_mfma_f32_16x16x32_bf16(av[dt], bp[qt], acco[dt][qt], 0, 0, 0);
    }
    #pragma unroll
    for (int mt = 0; mt < 4; ++mt)
        #pragma unroll
        for (int r = 0; r < 4; ++r) {
            float v = lp[mt][r];
            v += __shfl_xor(v, 1); v += __shfl_xor(v, 2);
            v += __shfl_xor(v, 4); v += __shfl_xor(v, 8);
            lp[mt][r] = v;
        }
    #pragma unroll
    for (int dt = 0; dt < 2; ++dt)
        #pragma unroll
        for (int qt = 0; qt < 4; ++qt) {
            int q = qt * 16 + lm;
            float4 t;
            t.x = acco[dt][qt][0]; t.y = acco[dt][qt][1];
            t.z = acco[dt][qt][2]; t.w = acco[dt][qt][3];
            *(float4*)&obuf[w][q * 36 + dt * 16 + quad * 4] = t;
        }
    if (lm == 0) {
        #pragma unroll
        for (int mt = 0; mt < 4; ++mt)
            #pragma unroll
            for (int r = 0; r < 4; ++r)
                lbuf[w * 64 + mt * 16 + quad * 4 + r] = lp[mt][r];
    }
    __syncthreads();
    int q = tid & 63, dg = tid >> 6;
    int blk = (b * 8 + h) * 2 + half;
    float l = lbuf[q] + lbuf[64 + q] + lbuf[128 + q] + lbuf[192 + q];
    float o[8];
    #pragma unroll
    for (int j = 0; j < 8; ++j) o[j] = 0.f;
    #pragma unroll
    for (int w2 = 0; w2 < 4; ++w2) {
        const float* src = &obuf[w2][q * 36 + dg * 8];
        #pragma unroll
        for (int j = 0; j < 8; ++j) o[j] += src[j];
    }
    float* dst = &o_half[(((size_t)blk * 64) + q) * 32 + dg * 8];
    #pragma unroll
    for (int j = 0; j < 8; ++j) dst[j] = o[j];
    if (dg == 0) l_half[blk * 64 + q] = l;
}

// ---------------- merge 2 halves + normalize -> ctx --------------------------
__global__ void k_attn_merge(const float* __restrict__ o_half,
                             const float* __restrict__ l_half,
                             float* __restrict__ ctx) {
    int bh = blockIdx.x;
    int b = bh >> 3, h = bh & 7;
    int tid = threadIdx.x;
    int q = tid & 63, dg = tid >> 6;
    size_t r0 = (((size_t)(bh * 2) * 64) + q) * 32 + dg * 8;
    size_t r1 = (((size_t)(bh * 2 + 1) * 64) + q) * 32 + dg * 8;
    float inv = 1.0f / (l_half[bh * 2 * 64 + q] + l_half[(bh * 2 + 1) * 64 + q]);
    float* dst = &ctx[((size_t)(b * 64 + q)) * 256 + h * 32 + dg * 8];
    #pragma unroll
    for (int j = 0; j < 8; ++j) dst[j] = (o_half[r0 + j] + o_half[r1 + j]) * inv;
}

// ---------------- out_proj + LN + meta + tw(bf16) + phase MLP + geometry -----
__global__ __launch_bounds__(256) void k_post(
        const float* __restrict__ ctx, const float* __restrict__ queries,
        const float* __restrict__ opwT, const float* __restrict__ opb,
        const float* __restrict__ lng, const float* __restrict__ lnb,
        const float* __restrict__ metag, const float* __restrict__ hshift,
        const float* __restrict__ twT, const float* __restrict__ tbv,
        const float* __restrict__ pw1T, const float* __restrict__ pb1,
        const float* __restrict__ pw2, const float* __restrict__ pb2,
        const float* __restrict__ p0a,
        bf16* __restrict__ twbf, float* __restrict__ out_amp,
        float* __restrict__ out_ppos, float* __restrict__ out_dip,
        float* __restrict__ out_vol) {
    __shared__ float cs[8][256];
    __shared__ float xs[8][256];
    __shared__ float qs[8][256];
    __shared__ float h1[8][128];
    __shared__ float ps[8][10];
    int tid = threadIdx.x;
    int n0 = blockIdx.x * 8, b = blockIdx.y;
    #pragma unroll
    for (int r = 0; r < 8; ++r)
        cs[r][tid] = ctx[(size_t)(b * 64 + n0 + r) * 256 + tid];
    __syncthreads();
    {
        int c = tid;
        float a[8];
        #pragma unroll
        for (int nn = 0; nn < 8; ++nn) a[nn] = opb[c];
        for (int k = 0; k < 256; ++k) {
            float w = opwT[k * 256 + c];
            #pragma unroll
            for (int nn = 0; nn < 8; ++nn) a[nn] += cs[nn][k] * w;
        }
        #pragma unroll
        for (int nn = 0; nn < 8; ++nn)
            xs[nn][c] = queries[(n0 + nn) * 256 + c] + a[nn];
    }
    __syncthreads();
    {
        int w = tid >> 6, lane = tid & 63;
        for (int i = 0; i < 2; ++i) {
            int nr = w + i * 4;
            float x0 = xs[nr][lane], x1 = xs[nr][lane + 64],
                  x2 = xs[nr][lane + 128], x3 = xs[nr][lane + 192];
            float s = x0 + x1 + x2 + x3;
            #pragma unroll
            for (int off = 32; off >= 1; off >>= 1) s += __shfl_xor(s, off);
            float mu = s * (1.0f / 256.0f);
            float e0 = x0 - mu, e1 = x1 - mu, e2 = x2 - mu, e3 = x3 - mu;
            float v = e0*e0 + e1*e1 + e2*e2 + e3*e3;
            #pragma unroll
            for (int off = 32; off >= 1; off >>= 1) v += __shfl_xor(v, off);
            float rstd = 1.0f / sqrtf(v * (1.0f / 256.0f) + 1e-5f);
            #pragma unroll
            for (int j = 0; j < 4; ++j) {
                int c = lane + 64 * j;
                qs[nr][c] = (xs[nr][c] - mu) * rstd * lng[c] + lnb[c] + metag[b * 256 + c];
            }
        }
    }
    __syncthreads();
    {
        int c = tid;
        float a[8];
        #pragma unroll
        for (int nn = 0; nn < 8; ++nn) a[nn] = tbv[c];
        for (int k = 0; k < 256; ++k) {
            float w = twT[k * 256 + c];
            #pragma unroll
            for (int nn = 0; nn < 8; ++nn) a[nn] += qs[nn][k] * w;
        }
        #pragma unroll
        for (int nn = 0; nn < 8; ++nn)
            twbf[(size_t)(b * 64 + n0 + nn) * 256 + c] = __float2bfloat16(a[nn]);
    }
    {
        int m = tid & 127, g = tid >> 7;
        float a[4];
        #pragma unroll
        for (int q4 = 0; q4 < 4; ++q4) a[q4] = pb1[m];
        for (int k = 0; k < 256; ++k) {
            float w = pw1T[k * 128 + m];
            #pragma unroll
            for (int q4 = 0; q4 < 4; ++q4) a[q4] += qs[g * 4 + q4][k] * w;
        }
        #pragma unroll
        for (int q4 = 0; q4 < 4; ++q4) h1[g * 4 + q4][m] = gelu_exact(a[q4]);
    }
    __syncthreads();
    if (tid < 80) {
        int nr = tid / 10, j = tid % 10;
        float s = pb2[j];
        for (int m = 0; m < 128; ++m) s += h1[nr][m] * pw2[j * 128 + m];
        ps[nr][j] = s;
    }
    __syncthreads();
    if (tid < 8) {
        int nr = tid;
        int gn = b * 64 + n0 + nr;
        #pragma unroll
        for (int j = 0; j < 3; ++j) {
            float delta = tanhf(ps[nr][j]) * 0.2f;
            out_ppos[gn * 3 + j] = p0a[(n0 + nr) * 3 + j] + delta + hshift[b * 4 + j];
        }
        float d0 = ps[nr][3], d1 = ps[nr][4], d2 = ps[nr][5];
        float dn = fmaxf(sqrtf(d0 * d0 + d1 * d1 + d2 * d2), 1e-6f);
        out_dip[gn * 3 + 0] = d0 / dn;
        out_dip[gn * 3 + 1] = d1 / dn;
        out_dip[gn * 3 + 2] = d2 / dn;
        #pragma unroll
        for (int j = 0; j < 3; ++j)
            out_vol[gn * 3 + j] = sigmoidf_(ps[nr][6 + j]) * 0.5f + 0.001f;
        out_amp[gn] = sigmoidf_(ps[nr][9]) + 0.0001f;
    }
}

// ---------------- argmax amplitude -> delay ----------------------------------
__global__ void k_delay(const float* __restrict__ out_amp, const float* __restrict__ out_ppos,
                        const float* __restrict__ wds, float* __restrict__ delay) {
    int b = blockIdx.x, lane = threadIdx.x;
    float v = out_amp[b * 64 + lane];
    int idx = lane;
    #pragma unroll
    for (int off = 1; off < 64; off <<= 1) {
        float ov = __shfl_xor(v, off);
        int oi = __shfl_xor(idx, off);
        if (ov > v || (ov == v && oi < idx)) { v = ov; idx = oi; }
    }
    float px[3], sa[3];
    #pragma unroll
    for (int j = 0; j < 3; ++j) px[j] = out_ppos[(b * 64 + lane) * 3 + j];
    #pragma unroll
    for (int j = 0; j < 3; ++j) sa[j] = __shfl(px[j], idx);
    float dx = px[0] - sa[0], dy = px[1] - sa[1], dz = px[2] - sa[2];
    float dist = sqrtf(dx * dx + dy * dy + dz * dz);
    float sp = log1pf(expf(wds[0]));
    delay[b * 64 + lane] = fminf(fmaxf(sp * dist, 0.f), 0.1f);
}

// ---------------- temporal logits via MFMA bf16 ------------------------------
__global__ __launch_bounds__(256) void k_temporal(
        const float* __restrict__ lf, const short* __restrict__ twbf,
        float* __restrict__ logits) {
    __shared__ __align__(16) short tws[64 * 264];
    __shared__ __align__(16) short lfs[32 * 132];
    int tid = threadIdx.x;
    int t0 = blockIdx.x * 128, b = blockIdx.y;
    int wave = tid >> 6, lane = tid & 63;
    int lm = lane & 15, quad = lane >> 4;

    #pragma unroll
    for (int i = 0; i < 8; ++i) {
        int id = i * 256 + tid;
        int n = id >> 5, c8 = id & 31;
        s16x8 v = *(const s16x8*)&twbf[(size_t)(b * 64 + n) * 256 + c8 * 8];
        *(s16x8*)&tws[n * 264 + c8 * 8] = v;
    }

    f32x4 acc[2][4];
    #pragma unroll
    for (int mi = 0; mi < 2; ++mi)
        #pragma unroll
        for (int ni = 0; ni < 4; ++ni) acc[mi][ni] = (f32x4)(0.0f);

    for (int ksi = 0; ksi < 8; ++ksi) {
        int c0 = ksi * 32;
        #pragma unroll
        for (int r = 0; r < 4; ++r) {
            int id = r * 256 + tid;
            int c = id >> 5, t4 = id & 31;
            float4 f = *(const float4*)&lf[((size_t)(b * 256 + c0 + c)) * 4096 + t0 + t4 * 4];
            ushort4 o;
            o.x = (unsigned short)f2bf_s(f.x);
            o.y = (unsigned short)f2bf_s(f.y);
            o.z = (unsigned short)f2bf_s(f.z);
            o.w = (unsigned short)f2bf_s(f.w);
            *(ushort4*)&lfs[c * 132 + t4 * 4] = o;
        }
        __syncthreads();
        #pragma unroll
        for (int mi = 0; mi < 2; ++mi) {
            int tl = wave * 32 + mi * 16 + lm;
            s16x8 af;
            #pragma unroll
            for (int j = 0; j < 8; ++j)
                af[j] = lfs[(quad * 8 + j) * 132 + tl];
            #pragma unroll
            for (int ni = 0; ni < 4; ++ni) {
                s16x8 bfr = *(const s16x8*)&tws[(ni * 16 + lm) * 264 + c0 + quad * 8];
                acc[mi][ni] = __builtin_amdgcn_mfma_f32_16x16x32_bf16(af, bfr, acc[mi][ni], 0, 0, 0);
            }
        }
        __syncthreads();
    }
    #pragma unroll
    for (int mi = 0; mi < 2; ++mi) {
        #pragma unroll
        for (int ni = 0; ni < 4; ++ni) {
            int n = ni * 16 + lm;
            int t = t0 + wave * 32 + mi * 16 + quad * 4;
            float4 o;
            o.x = acc[mi][ni][0] * 0.0625f;
            o.y = acc[mi][ni][1] * 0.0625f;
            o.z = acc[mi][ni][2] * 0.0625f;
            o.w = acc[mi][ni][3] * 0.0625f;
            *reinterpret_cast<float4*>(&logits[(size_t)(b * 64 + n) * 4096 + t]) = o;
        }
    }
}

// ---------------- warped sampling + sigmoid envelope -------------------------
__global__ void k_envelope(const float* __restrict__ logits, const float* __restrict__ delay,
                           const float* __restrict__ ebp, float* __restrict__ env) {
    int blk = blockIdx.x;
    int bn = blk >> 2, seg = blk & 3;
    int tid = threadIdx.x;
    float dl = delay[bn];
    float eb = ebp[0];
    const float* gl = logits + (size_t)bn * 4096;
    int t_base = seg * 1024 + tid * 4;
    float ov[4];
    #pragma unroll
    for (int u = 0; u < 4; ++u) {
        int t = t_base + u;
        float xb = fmaf((float)t, 2.0f / 4095.0f, -1.0f);
        float xp = (xb - dl + 1.0f) * 2047.5f;
        float x0f = floorf(xp);
        int x0 = (int)x0f;
        float w1 = xp - x0f, w0 = 1.0f - w1;
        float g0 = (x0 >= 0 && x0 <= 4095) ? gl[x0] : 0.f;
        int x1 = x0 + 1;
        float g1 = (x1 >= 0 && x1 <= 4095) ? gl[x1] : 0.f;
        float sh = w0 * g0 + w1 * g1;
        ov[u] = 1.0f / (1.0f + __expf(-(sh + eb)));
    }
    float4 o; o.x = ov[0]; o.y = ov[1]; o.z = ov[2]; o.w = ov[3];
    *reinterpret_cast<float4*>(&env[(size_t)bn * 4096 + t_base]) = o;
}

extern "C" void kernel_launch(void* const* d_in, const int* in_sizes, int n_in,
                              void* d_out, int out_size, void* d_ws, size_t ws_size,
                              hipStream_t stream) {
    const float* lf   = (const float*)d_in[0];
    const float* gf   = (const float*)d_in[1];
    const float* meta = (const float*)d_in[2];
    const float* qrs  = (const float*)d_in[3];
    const float* p0a  = (const float*)d_in[4];
    const float* ipw  = (const float*)d_in[5];
    const float* ipb  = (const float*)d_in[6];
    const float* opw  = (const float*)d_in[7];
    const float* opb  = (const float*)d_in[8];
    const float* lng  = (const float*)d_in[9];
    const float* lnb  = (const float*)d_in[10];
    const float* mw   = (const float*)d_in[11];
    const float* mb   = (const float*)d_in[12];
    const float* twm  = (const float*)d_in[13];
    const float* tbv  = (const float*)d_in[14];
    const float* sw   = (const float*)d_in[15];
    const float* sb   = (const float*)d_in[16];
    const float* pw1  = (const float*)d_in[17];
    const float* pb1  = (const float*)d_in[18];
    const float* pw2  = (const float*)d_in[19];
    const float* pb2  = (const float*)d_in[20];
    const float* wds  = (const float*)d_in[21];
    const float* ebp  = (const float*)d_in[22];

    char* ws = (char*)d_ws;
    short* kvh    = (short*)(ws);                    // 16,777,216  K bf16 [b][t][256]
    short* vTg    = (short*)(ws + 16777216);         // 16,777,216  V^T bf16 [b][n][1024]
    short* gfT    = (short*)(ws + 33554432);         // 16,777,216  bf16 [b][t][256]
    float* logits = (float*)(ws + 50331648);         // 33,554,432
    float* o_half = (float*)(ws + 83886080);         //  4,194,304
    float* l_half = (float*)(ws + 88080384);         //    131,072
    float* ctx    = (float*)(ws + 88211456);         //  2,097,152
    short* twbf   = (short*)(ws + 90308608);         //  1,048,576
    float* qh     = (float*)(ws + 91357184);         //     65,536
    float* gmean  = (float*)(ws + 91422720);         //     32,768
    float* metag  = (float*)(ws + 91455488);         //     32,768
    float* hshift = (float*)(ws + 91488256);         //        512
    float* delay  = (float*)(ws + 91488768);         //      8,192
    float* opwT   = (float*)(ws + 91496960);         //    262,144
    float* twT    = (float*)(ws + 91759104);         //    262,144
    float* pw1T   = (float*)(ws + 92021248);         //    131,072
    float* wqT    = (float*)(ws + 92152320);         //    262,144
    bf16*  wkvK   = (bf16*)(ws + 92414464);          //    131,072
    bf16*  wkvV   = (bf16*)(ws + 92545536);          //    131,072

    float* out_amp  = (float*)d_out;
    float* out_ppos = out_amp + 2048;
    float* out_dip  = out_amp + 8192;
    float* out_vol  = out_amp + 14336;
    float* env      = out_amp + 20480;

    k_transpose<<<384, 256, 0, stream>>>(ipw, opw, twm, pw1, wqT, opwT, twT, pw1T);
    k_wcvt<<<256, 256, 0, stream>>>(ipw, wkvK, wkvV);
    k_gft<<<dim3(16, 4, 32), 256, 0, stream>>>(gf, (bf16*)gfT);
    k_gmean<<<8192, 64, 0, stream>>>(gf, gmean);
    k_qh<<<64, 256, 0, stream>>>(qrs, wqT, ipb, qh);
    k_metahs<<<32, 256, 0, stream>>>(meta, mw, mb, gmean, sw, sb, metag, hshift);
    k_kproj<<<dim3(8, 4, 32), 256, 0, stream>>>(gfT, (const short*)wkvK, ipb, kvh);
    k_vproj<<<dim3(8, 4, 32), 256, 0, stream>>>(gfT, (const short*)wkvV, ipb, vTg);
    k_attn<<<dim3(2, 8, 32), 256, 0, stream>>>(kvh, vTg, qh, o_half, l_half);
    k_attn_merge<<<256, 256, 0, stream>>>(o_half, l_half, ctx);
    k_post<<<dim3(8, 32), 256, 0, stream>>>(ctx, qrs, opwT, opb, lng, lnb, metag, hshift,
                                            twT, tbv, pw1T, pb1, pw2, pb2, p0a,
                                            (bf16*)twbf, out_amp, out_ppos, out_dip, out_vol);
    k_delay<<<32, 64, 0, stream>>>(out_amp, out_ppos, wds, delay);
    k_temporal<<<dim3(32, 32), 256, 0, stream>>>(lf, (const short*)twbf, logits);
    k_envelope<<<8192, 256, 0, stream>>>(logits, delay, ebp, env);
}

// Round 5
// 420.282 us; speedup vs baseline: 1.5740x; 1.0505x over previous
//
#include <hip/hip_runtime.h>
#include <hip/hip_bf16.h>
#include <math.h>

typedef __hip_bfloat16 bf16;
typedef short s16x8 __attribute__((ext_vector_type(8)));
typedef float f32x4 __attribute__((ext_vector_type(4)));

#define NDIM 256
#define NTG 1024
#define NT 4096

__device__ __forceinline__ float gelu_exact(float x) {
    return 0.5f * x * (1.0f + erff(x * 0.70710678118654752440f));
}
__device__ __forceinline__ float sigmoidf_(float x) {
    return 1.0f / (1.0f + __expf(-x));
}
__device__ __forceinline__ short f2bf_s(float x) {
    union { bf16 h; short s; } cv;
    cv.h = __float2bfloat16(x);
    return cv.s;
}
__device__ __forceinline__ float bf2f(short s) {
    union { bf16 h; short s; } cv;
    cv.s = s;
    return __bfloat162float(cv.h);
}

// ---------------- prep: weight transposes + bf16 cvt + qh + zero gmean -------
// blocks [0,384): transposes; [384,640): wkv cvt; [640,704): qh; [704,712): zero
__global__ __launch_bounds__(256) void k_prep(
        const float* __restrict__ ipw, const float* __restrict__ opw,
        const float* __restrict__ twm, const float* __restrict__ pw1,
        const float* __restrict__ queries, const float* __restrict__ ipb,
        float* __restrict__ opwT, float* __restrict__ twT, float* __restrict__ pw1T,
        bf16* __restrict__ wkvK, bf16* __restrict__ wkvV,
        float* __restrict__ qh, float* __restrict__ gmean) {
    int blk = blockIdx.x, tid = threadIdx.x;
    if (blk < 384) {
        int id = blk * 256 + tid;
        if (id < 65536) {
            int k = id >> 8, c = id & 255;
            opwT[id] = opw[c * 256 + k];
            twT[id]  = twm[c * 256 + k];
        } else {
            int id2 = id - 65536;
            int k = id2 >> 7, m = id2 & 127;
            pw1T[id2] = pw1[m * 256 + k];
        }
    } else if (blk < 640) {
        int id = (blk - 384) * 256 + tid;
        wkvK[id] = __float2bfloat16(ipw[65536 + id]);
        wkvV[id] = __float2bfloat16(ipw[131072 + id]);
    } else if (blk < 704) {
        __shared__ float qrow[256];
        int n = blk - 640, c = tid;
        qrow[c] = queries[n * 256 + c];
        __syncthreads();
        float s = ipb[c];
        const float* wr = ipw + c * 256;
        for (int k = 0; k < 256; ++k) s += qrow[k] * wr[k];
        qh[n * 256 + c] = s;
    } else {
        gmean[(blk - 704) * 256 + tid] = 0.f;
    }
}

// ---------------- gf -> gfT bf16 [b][t][c]  +  gmean atomic accumulation -----
__global__ __launch_bounds__(256) void k_gft(const float* __restrict__ gf,
                                             bf16* __restrict__ gfT,
                                             float* __restrict__ gmean) {
    __shared__ float tile[64][65];
    int tid = threadIdx.x;
    int t0 = blockIdx.x * 64, c0 = blockIdx.y * 64, b = blockIdx.z;
    int tt = tid & 63, ci = tid >> 6;
    #pragma unroll
    for (int r = 0; r < 16; ++r) {
        int cl = ci * 16 + r;
        tile[cl][tt] = gf[((size_t)(b * 256 + c0 + cl)) * NTG + t0 + tt];
    }
    __syncthreads();
    int cc = tid & 63, ti = tid >> 6;
    #pragma unroll
    for (int r = 0; r < 16; ++r) {
        int tl = ti * 16 + r;
        gfT[((size_t)(b * 1024 + t0 + tl)) * 256 + c0 + cc] =
            __float2bfloat16(tile[cc][tl]);
    }
    // gmean partial: thread (cc, ti) sums 16 t-values for channel cc
    float ps = 0.f;
    #pragma unroll
    for (int r = 0; r < 16; ++r) ps += tile[cc][ti * 16 + r];
    atomicAdd(&gmean[b * 256 + c0 + cc], ps * (1.0f / 1024.0f));
}

// ---------------- meta gelu + heart_shift ------------------------------------
__global__ void k_metahs(const float* __restrict__ meta, const float* __restrict__ mw,
                         const float* __restrict__ mb, const float* __restrict__ gmean,
                         const float* __restrict__ sw, const float* __restrict__ sb,
                         float* __restrict__ metag, float* __restrict__ hshift) {
    int b = blockIdx.x, c = threadIdx.x;
    float s = mb[c];
    #pragma unroll
    for (int j = 0; j < 6; ++j) s += meta[b * 6 + j] * mw[c * 6 + j];
    metag[b * 256 + c] = gelu_exact(s);
    if (c < 3) {
        float t = sb[c];
        const float* gm = gmean + b * 256;
        for (int k = 0; k < 256; ++k) t += gm[k] * sw[c * 256 + k];
        hshift[b * 4 + c] = tanhf(t) * 0.3f;
    }
}

// ---------------- fused K/V projection (MFMA bf16) ---------------------------
// blockIdx.y: bit2 selects K(0)/V(1); low 2 bits select n-tile of 64.
__global__ __launch_bounds__(256) void k_kv(
        const short* __restrict__ gfT, const short* __restrict__ wkvK,
        const short* __restrict__ wkvV, const float* __restrict__ ipb,
        short* __restrict__ kvh, short* __restrict__ vTg) {
    int tid = threadIdx.x;
    int w = tid >> 6, lane = tid & 63, lm = lane & 15, quad = lane >> 4;
    int t0 = blockIdx.x * 128 + w * 32;
    int sel = blockIdx.y >> 2;
    int n0 = (blockIdx.y & 3) * 64;
    int b = blockIdx.z;
    if (sel == 0) {
        f32x4 acc[4][2];
        #pragma unroll
        for (int ni = 0; ni < 4; ++ni)
            #pragma unroll
            for (int mt = 0; mt < 2; ++mt) acc[ni][mt] = (f32x4)(0.0f);
        #pragma unroll
        for (int ks = 0; ks < 8; ++ks) {
            int c = ks * 32 + quad * 8;
            s16x8 bg[2];
            #pragma unroll
            for (int mt = 0; mt < 2; ++mt)
                bg[mt] = *(const s16x8*)&gfT[((size_t)(b * 1024 + t0 + mt * 16 + lm)) * 256 + c];
            #pragma unroll
            for (int ni = 0; ni < 4; ++ni) {
                s16x8 aw = *(const s16x8*)&wkvK[(n0 + ni * 16 + lm) * 256 + c];
                #pragma unroll
                for (int mt = 0; mt < 2; ++mt)
                    acc[ni][mt] = __builtin_amdgcn_mfma_f32_16x16x32_bf16(aw, bg[mt], acc[ni][mt], 0, 0, 0);
            }
        }
        #pragma unroll
        for (int ni = 0; ni < 4; ++ni) {
            int nb4 = n0 + ni * 16 + quad * 4;
            float4 bias = *(const float4*)&ipb[256 + nb4];
            #pragma unroll
            for (int mt = 0; mt < 2; ++mt) {
                int t = t0 + mt * 16 + lm;
                ushort4 o;
                o.x = (unsigned short)f2bf_s(acc[ni][mt][0] + bias.x);
                o.y = (unsigned short)f2bf_s(acc[ni][mt][1] + bias.y);
                o.z = (unsigned short)f2bf_s(acc[ni][mt][2] + bias.z);
                o.w = (unsigned short)f2bf_s(acc[ni][mt][3] + bias.w);
                *(ushort4*)&kvh[((size_t)(b * 1024 + t)) * 256 + nb4] = o;
            }
        }
    } else {
        f32x4 acc[2][4];
        #pragma unroll
        for (int mt = 0; mt < 2; ++mt)
            #pragma unroll
            for (int ni = 0; ni < 4; ++ni) acc[mt][ni] = (f32x4)(0.0f);
        #pragma unroll
        for (int ks = 0; ks < 8; ++ks) {
            int c = ks * 32 + quad * 8;
            s16x8 ag[2];
            #pragma unroll
            for (int mt = 0; mt < 2; ++mt)
                ag[mt] = *(const s16x8*)&gfT[((size_t)(b * 1024 + t0 + mt * 16 + lm)) * 256 + c];
            #pragma unroll
            for (int ni = 0; ni < 4; ++ni) {
                s16x8 bw = *(const s16x8*)&wkvV[(n0 + ni * 16 + lm) * 256 + c];
                #pragma unroll
                for (int mt = 0; mt < 2; ++mt)
                    acc[mt][ni] = __builtin_amdgcn_mfma_f32_16x16x32_bf16(ag[mt], bw, acc[mt][ni], 0, 0, 0);
            }
        }
        #pragma unroll
        for (int ni = 0; ni < 4; ++ni) {
            int nv = n0 + ni * 16 + lm;
            float bias = ipb[512 + nv];
            #pragma unroll
            for (int mt = 0; mt < 2; ++mt) {
                int t4 = t0 + mt * 16 + quad * 4;
                ushort4 o;
                o.x = (unsigned short)f2bf_s(acc[mt][ni][0] + bias);
                o.y = (unsigned short)f2bf_s(acc[mt][ni][1] + bias);
                o.z = (unsigned short)f2bf_s(acc[mt][ni][2] + bias);
                o.w = (unsigned short)f2bf_s(acc[mt][ni][3] + bias);
                *(ushort4*)&vTg[((size_t)(b * 256 + nv)) * 1024 + t4] = o;
            }
        }
    }
}

// ---------------- MFMA attention: grid (half, h, b), 4 waves x 128 keys ------
__global__ __launch_bounds__(256) void k_attn(
        const short* __restrict__ kvh, const short* __restrict__ vTg,
        const float* __restrict__ qh,
        float* __restrict__ o_half, float* __restrict__ l_half) {
    __shared__ short pT[4][64 * 40];
    __shared__ float obuf[4][64 * 36];
    __shared__ float lbuf[4 * 64];
    int tid = threadIdx.x;
    int w = tid >> 6, lane = tid & 63, lm = lane & 15, quad = lane >> 4;
    int half = blockIdx.x, h = blockIdx.y, b = blockIdx.z;
    s16x8 aq[4];
    #pragma unroll
    for (int mt = 0; mt < 4; ++mt) {
        const float* qp = qh + (mt * 16 + lm) * 256 + h * 32 + quad * 8;
        #pragma unroll
        for (int j = 0; j < 8; ++j) aq[mt][j] = f2bf_s(qp[j]);
    }
    f32x4 acco[2][4];
    #pragma unroll
    for (int dt = 0; dt < 2; ++dt)
        #pragma unroll
        for (int qt = 0; qt < 4; ++qt) acco[dt][qt] = (f32x4)(0.0f);
    float lp[4][4];
    #pragma unroll
    for (int mt = 0; mt < 4; ++mt)
        #pragma unroll
        for (int r = 0; r < 4; ++r) lp[mt][r] = 0.f;
    const float scale = 0.17677669529663687f;   // 1/sqrt(32)
    int kb = half * 512 + w * 128;
    for (int ch = 0; ch < 4; ++ch) {
        int n0 = kb + ch * 32;
        #pragma unroll
        for (int nt = 0; nt < 2; ++nt) {
            int key = n0 + nt * 16 + lm;
            s16x8 bk = *(const s16x8*)&kvh[((size_t)(b * 1024 + key)) * 256 + h * 32 + quad * 8];
            f32x4 zero = {0.f, 0.f, 0.f, 0.f};
            #pragma unroll
            for (int mt = 0; mt < 4; ++mt) {
                f32x4 S = __builtin_amdgcn_mfma_f32_16x16x32_bf16(aq[mt], bk, zero, 0, 0, 0);
                #pragma unroll
                for (int r = 0; r < 4; ++r) {
                    float e = __expf(S[r] * scale);
                    lp[mt][r] += e;
                    pT[w][(mt * 16 + quad * 4 + r) * 40 + nt * 16 + lm] = f2bf_s(e);
                }
            }
        }
        s16x8 av[2], bp[4];
        #pragma unroll
        for (int dt = 0; dt < 2; ++dt)
            av[dt] = *(const s16x8*)&vTg[((size_t)(b * 256 + h * 32 + dt * 16 + lm)) * 1024 + n0 + quad * 8];
        #pragma unroll
        for (int qt = 0; qt < 4; ++qt)
            bp[qt] = *(const s16x8*)&pT[w][(qt * 16 + lm) * 40 + quad * 8];
        #pragma unroll
        for (int dt = 0; dt < 2; ++dt)
            #pragma unroll
            for (int qt = 0; qt < 4; ++qt)
                acco[dt][qt] = __builtin_amdgcn_mfma_f32_16x16x32_bf16(av[dt], bp[qt], acco[dt][qt], 0, 0, 0);
    }
    #pragma unroll
    for (int mt = 0; mt < 4; ++mt)
        #pragma unroll
        for (int r = 0; r < 4; ++r) {
            float v = lp[mt][r];
            v += __shfl_xor(v, 1); v += __shfl_xor(v, 2);
            v += __shfl_xor(v, 4); v += __shfl_xor(v, 8);
            lp[mt][r] = v;
        }
    #pragma unroll
    for (int dt = 0; dt < 2; ++dt)
        #pragma unroll
        for (int qt = 0; qt < 4; ++qt) {
            int q = qt * 16 + lm;
            float4 t;
            t.x = acco[dt][qt][0]; t.y = acco[dt][qt][1];
            t.z = acco[dt][qt][2]; t.w = acco[dt][qt][3];
            *(float4*)&obuf[w][q * 36 + dt * 16 + quad * 4] = t;
        }
    if (lm == 0) {
        #pragma unroll
        for (int mt = 0; mt < 4; ++mt)
            #pragma unroll
            for (int r = 0; r < 4; ++r)
                lbuf[w * 64 + mt * 16 + quad * 4 + r] = lp[mt][r];
    }
    __syncthreads();
    int q = tid & 63, dg = tid >> 6;
    int blk = (b * 8 + h) * 2 + half;
    float l = lbuf[q] + lbuf[64 + q] + lbuf[128 + q] + lbuf[192 + q];
    float o[8];
    #pragma unroll
    for (int j = 0; j < 8; ++j) o[j] = 0.f;
    #pragma unroll
    for (int w2 = 0; w2 < 4; ++w2) {
        const float* src = &obuf[w2][q * 36 + dg * 8];
        #pragma unroll
        for (int j = 0; j < 8; ++j) o[j] += src[j];
    }
    float* dst = &o_half[(((size_t)blk * 64) + q) * 32 + dg * 8];
    #pragma unroll
    for (int j = 0; j < 8; ++j) dst[j] = o[j];
    if (dg == 0) l_half[blk * 64 + q] = l;
}

// ---------------- out_proj + LN + meta + tw(bf16) + phase MLP + geometry -----
// (attention merge folded into ctx staging)
__global__ __launch_bounds__(256) void k_post(
        const float* __restrict__ o_half, const float* __restrict__ l_half,
        const float* __restrict__ queries,
        const float* __restrict__ opwT, const float* __restrict__ opb,
        const float* __restrict__ lng, const float* __restrict__ lnb,
        const float* __restrict__ metag, const float* __restrict__ hshift,
        const float* __restrict__ twT, const float* __restrict__ tbv,
        const float* __restrict__ pw1T, const float* __restrict__ pb1,
        const float* __restrict__ pw2, const float* __restrict__ pb2,
        const float* __restrict__ p0a,
        bf16* __restrict__ twbf, float* __restrict__ out_amp,
        float* __restrict__ out_ppos, float* __restrict__ out_dip,
        float* __restrict__ out_vol) {
    __shared__ float cs[8][256];
    __shared__ float xs[8][256];
    __shared__ float qs[8][256];
    __shared__ float h1[8][128];
    __shared__ float ps[8][10];
    int tid = threadIdx.x;
    int n0 = blockIdx.x * 8, b = blockIdx.y;
    {
        int h = tid >> 5, d = tid & 31;
        int blk0 = (b * 8 + h) * 2;
        #pragma unroll
        for (int r = 0; r < 8; ++r) {
            int q = n0 + r;
            float l = l_half[blk0 * 64 + q] + l_half[(blk0 + 1) * 64 + q];
            float v0 = o_half[(((size_t)blk0 * 64) + q) * 32 + d];
            float v1 = o_half[(((size_t)(blk0 + 1) * 64) + q) * 32 + d];
            cs[r][tid] = (v0 + v1) / l;
        }
    }
    __syncthreads();
    {
        int c = tid;
        float a[8];
        #pragma unroll
        for (int nn = 0; nn < 8; ++nn) a[nn] = opb[c];
        for (int k = 0; k < 256; ++k) {
            float w = opwT[k * 256 + c];
            #pragma unroll
            for (int nn = 0; nn < 8; ++nn) a[nn] += cs[nn][k] * w;
        }
        #pragma unroll
        for (int nn = 0; nn < 8; ++nn)
            xs[nn][c] = queries[(n0 + nn) * 256 + c] + a[nn];
    }
    __syncthreads();
    {
        int w = tid >> 6, lane = tid & 63;
        for (int i = 0; i < 2; ++i) {
            int nr = w + i * 4;
            float x0 = xs[nr][lane], x1 = xs[nr][lane + 64],
                  x2 = xs[nr][lane + 128], x3 = xs[nr][lane + 192];
            float s = x0 + x1 + x2 + x3;
            #pragma unroll
            for (int off = 32; off >= 1; off >>= 1) s += __shfl_xor(s, off);
            float mu = s * (1.0f / 256.0f);
            float e0 = x0 - mu, e1 = x1 - mu, e2 = x2 - mu, e3 = x3 - mu;
            float v = e0*e0 + e1*e1 + e2*e2 + e3*e3;
            #pragma unroll
            for (int off = 32; off >= 1; off >>= 1) v += __shfl_xor(v, off);
            float rstd = 1.0f / sqrtf(v * (1.0f / 256.0f) + 1e-5f);
            #pragma unroll
            for (int j = 0; j < 4; ++j) {
                int c = lane + 64 * j;
                qs[nr][c] = (xs[nr][c] - mu) * rstd * lng[c] + lnb[c] + metag[b * 256 + c];
            }
        }
    }
    __syncthreads();
    {
        int c = tid;
        float a[8];
        #pragma unroll
        for (int nn = 0; nn < 8; ++nn) a[nn] = tbv[c];
        for (int k = 0; k < 256; ++k) {
            float w = twT[k * 256 + c];
            #pragma unroll
            for (int nn = 0; nn < 8; ++nn) a[nn] += qs[nn][k] * w;
        }
        #pragma unroll
        for (int nn = 0; nn < 8; ++nn)
            twbf[(size_t)(b * 64 + n0 + nn) * 256 + c] = __float2bfloat16(a[nn]);
    }
    {
        int m = tid & 127, g = tid >> 7;
        float a[4];
        #pragma unroll
        for (int q4 = 0; q4 < 4; ++q4) a[q4] = pb1[m];
        for (int k = 0; k < 256; ++k) {
            float w = pw1T[k * 128 + m];
            #pragma unroll
            for (int q4 = 0; q4 < 4; ++q4) a[q4] += qs[g * 4 + q4][k] * w;
        }
        #pragma unroll
        for (int q4 = 0; q4 < 4; ++q4) h1[g * 4 + q4][m] = gelu_exact(a[q4]);
    }
    __syncthreads();
    if (tid < 80) {
        int nr = tid / 10, j = tid % 10;
        float s = pb2[j];
        for (int m = 0; m < 128; ++m) s += h1[nr][m] * pw2[j * 128 + m];
        ps[nr][j] = s;
    }
    __syncthreads();
    if (tid < 8) {
        int nr = tid;
        int gn = b * 64 + n0 + nr;
        #pragma unroll
        for (int j = 0; j < 3; ++j) {
            float delta = tanhf(ps[nr][j]) * 0.2f;
            out_ppos[gn * 3 + j] = p0a[(n0 + nr) * 3 + j] + delta + hshift[b * 4 + j];
        }
        float d0 = ps[nr][3], d1 = ps[nr][4], d2 = ps[nr][5];
        float dn = fmaxf(sqrtf(d0 * d0 + d1 * d1 + d2 * d2), 1e-6f);
        out_dip[gn * 3 + 0] = d0 / dn;
        out_dip[gn * 3 + 1] = d1 / dn;
        out_dip[gn * 3 + 2] = d2 / dn;
        #pragma unroll
        for (int j = 0; j < 3; ++j)
            out_vol[gn * 3 + j] = sigmoidf_(ps[nr][6 + j]) * 0.5f + 0.001f;
        out_amp[gn] = sigmoidf_(ps[nr][9]) + 0.0001f;
    }
}

// ---------------- temporal logits via MFMA bf16 -> bf16 logits ---------------
__global__ __launch_bounds__(256) void k_temporal(
        const float* __restrict__ lf, const short* __restrict__ twbf,
        short* __restrict__ logits) {
    __shared__ __align__(16) short tws[64 * 264];
    __shared__ __align__(16) short lfs[32 * 132];
    int tid = threadIdx.x;
    int t0 = blockIdx.x * 128, b = blockIdx.y;
    int wave = tid >> 6, lane = tid & 63;
    int lm = lane & 15, quad = lane >> 4;

    #pragma unroll
    for (int i = 0; i < 8; ++i) {
        int id = i * 256 + tid;
        int n = id >> 5, c8 = id & 31;
        s16x8 v = *(const s16x8*)&twbf[(size_t)(b * 64 + n) * 256 + c8 * 8];
        *(s16x8*)&tws[n * 264 + c8 * 8] = v;
    }

    f32x4 acc[2][4];
    #pragma unroll
    for (int mi = 0; mi < 2; ++mi)
        #pragma unroll
        for (int ni = 0; ni < 4; ++ni) acc[mi][ni] = (f32x4)(0.0f);

    for (int ksi = 0; ksi < 8; ++ksi) {
        int c0 = ksi * 32;
        #pragma unroll
        for (int r = 0; r < 4; ++r) {
            int id = r * 256 + tid;
            int c = id >> 5, t4 = id & 31;
            float4 f = *(const float4*)&lf[((size_t)(b * 256 + c0 + c)) * 4096 + t0 + t4 * 4];
            ushort4 o;
            o.x = (unsigned short)f2bf_s(f.x);
            o.y = (unsigned short)f2bf_s(f.y);
            o.z = (unsigned short)f2bf_s(f.z);
            o.w = (unsigned short)f2bf_s(f.w);
            *(ushort4*)&lfs[c * 132 + t4 * 4] = o;
        }
        __syncthreads();
        #pragma unroll
        for (int mi = 0; mi < 2; ++mi) {
            int tl = wave * 32 + mi * 16 + lm;
            s16x8 af;
            #pragma unroll
            for (int j = 0; j < 8; ++j)
                af[j] = lfs[(quad * 8 + j) * 132 + tl];
            #pragma unroll
            for (int ni = 0; ni < 4; ++ni) {
                s16x8 bfr = *(const s16x8*)&tws[(ni * 16 + lm) * 264 + c0 + quad * 8];
                acc[mi][ni] = __builtin_amdgcn_mfma_f32_16x16x32_bf16(af, bfr, acc[mi][ni], 0, 0, 0);
            }
        }
        __syncthreads();
    }
    #pragma unroll
    for (int mi = 0; mi < 2; ++mi) {
        #pragma unroll
        for (int ni = 0; ni < 4; ++ni) {
            int n = ni * 16 + lm;
            int t = t0 + wave * 32 + mi * 16 + quad * 4;
            ushort4 o;
            o.x = (unsigned short)f2bf_s(acc[mi][ni][0] * 0.0625f);
            o.y = (unsigned short)f2bf_s(acc[mi][ni][1] * 0.0625f);
            o.z = (unsigned short)f2bf_s(acc[mi][ni][2] * 0.0625f);
            o.w = (unsigned short)f2bf_s(acc[mi][ni][3] * 0.0625f);
            *(ushort4*)&logits[(size_t)(b * 64 + n) * 4096 + t] = o;
        }
    }
}

// ---------------- warped sampling + sigmoid envelope (+ inline delay) --------
__global__ void k_envelope(const short* __restrict__ logits,
                           const float* __restrict__ out_amp,
                           const float* __restrict__ out_ppos,
                           const float* __restrict__ wds,
                           const float* __restrict__ ebp,
                           float* __restrict__ env) {
    int blk = blockIdx.x;
    int bn = blk >> 2, seg = blk & 3;
    int b = bn >> 6, n = bn & 63;
    int tid = threadIdx.x;
    int lane = tid & 63;
    // inline delay computation (redundant per wave)
    float v = out_amp[b * 64 + lane];
    int idx = lane;
    #pragma unroll
    for (int off = 1; off < 64; off <<= 1) {
        float ov = __shfl_xor(v, off);
        int oi = __shfl_xor(idx, off);
        if (ov > v || (ov == v && oi < idx)) { v = ov; idx = oi; }
    }
    float dx = out_ppos[(b * 64 + n) * 3 + 0] - out_ppos[(b * 64 + idx) * 3 + 0];
    float dy = out_ppos[(b * 64 + n) * 3 + 1] - out_ppos[(b * 64 + idx) * 3 + 1];
    float dz = out_ppos[(b * 64 + n) * 3 + 2] - out_ppos[(b * 64 + idx) * 3 + 2];
    float dist = sqrtf(dx * dx + dy * dy + dz * dz);
    float sp = log1pf(expf(wds[0]));
    float dl = fminf(fmaxf(sp * dist, 0.f), 0.1f);
    float eb = ebp[0];
    const short* gl = logits + (size_t)bn * 4096;
    int t_base = seg * 1024 + tid * 4;
    float ov4[4];
    #pragma unroll
    for (int u = 0; u < 4; ++u) {
        int t = t_base + u;
        float xb = fmaf((float)t, 2.0f / 4095.0f, -1.0f);
        float xp = (xb - dl + 1.0f) * 2047.5f;
        float x0f = floorf(xp);
        int x0 = (int)x0f;
        float w1 = xp - x0f, w0 = 1.0f - w1;
        float g0 = (x0 >= 0 && x0 <= 4095) ? bf2f(gl[x0]) : 0.f;
        int x1 = x0 + 1;
        float g1 = (x1 >= 0 && x1 <= 4095) ? bf2f(gl[x1]) : 0.f;
        float sh = w0 * g0 + w1 * g1;
        ov4[u] = 1.0f / (1.0f + __expf(-(sh + eb)));
    }
    float4 o; o.x = ov4[0]; o.y = ov4[1]; o.z = ov4[2]; o.w = ov4[3];
    *reinterpret_cast<float4*>(&env[(size_t)bn * 4096 + t_base]) = o;
}

extern "C" void kernel_launch(void* const* d_in, const int* in_sizes, int n_in,
                              void* d_out, int out_size, void* d_ws, size_t ws_size,
                              hipStream_t stream) {
    const float* lf   = (const float*)d_in[0];
    const float* gf   = (const float*)d_in[1];
    const float* meta = (const float*)d_in[2];
    const float* qrs  = (const float*)d_in[3];
    const float* p0a  = (const float*)d_in[4];
    const float* ipw  = (const float*)d_in[5];
    const float* ipb  = (const float*)d_in[6];
    const float* opw  = (const float*)d_in[7];
    const float* opb  = (const float*)d_in[8];
    const float* lng  = (const float*)d_in[9];
    const float* lnb  = (const float*)d_in[10];
    const float* mw   = (const float*)d_in[11];
    const float* mb   = (const float*)d_in[12];
    const float* twm  = (const float*)d_in[13];
    const float* tbv  = (const float*)d_in[14];
    const float* sw   = (const float*)d_in[15];
    const float* sb   = (const float*)d_in[16];
    const float* pw1  = (const float*)d_in[17];
    const float* pb1  = (const float*)d_in[18];
    const float* pw2  = (const float*)d_in[19];
    const float* pb2  = (const float*)d_in[20];
    const float* wds  = (const float*)d_in[21];
    const float* ebp  = (const float*)d_in[22];

    char* ws = (char*)d_ws;
    short* kvh    = (short*)(ws);                    // 16,777,216  K bf16 [b][t][256]
    short* vTg    = (short*)(ws + 16777216);         // 16,777,216  V^T bf16 [b][n][1024]
    short* gfT    = (short*)(ws + 33554432);         // 16,777,216  bf16 [b][t][256]
    short* logits = (short*)(ws + 50331648);         // 16,777,216  bf16 [b*n][4096]
    float* o_half = (float*)(ws + 67108864);         //  4,194,304
    float* l_half = (float*)(ws + 71303168);         //    131,072
    short* twbf   = (short*)(ws + 71434240);         //  1,048,576
    float* qh     = (float*)(ws + 72482816);         //     65,536
    float* gmean  = (float*)(ws + 72548352);         //     32,768
    float* metag  = (float*)(ws + 72581120);         //     32,768
    float* hshift = (float*)(ws + 72613888);         //        512
    float* opwT   = (float*)(ws + 72614400);         //    262,144
    float* twT    = (float*)(ws + 72876544);         //    262,144
    float* pw1T   = (float*)(ws + 73138688);         //    131,072
    short* wkvK   = (short*)(ws + 73269760);         //    131,072
    short* wkvV   = (short*)(ws + 73400832);         //    131,072

    float* out_amp  = (float*)d_out;
    float* out_ppos = out_amp + 2048;
    float* out_dip  = out_amp + 8192;
    float* out_vol  = out_amp + 14336;
    float* env      = out_amp + 20480;

    k_prep<<<712, 256, 0, stream>>>(ipw, opw, twm, pw1, qrs, ipb,
                                    opwT, twT, pw1T, (bf16*)wkvK, (bf16*)wkvV,
                                    qh, gmean);
    k_gft<<<dim3(16, 4, 32), 256, 0, stream>>>(gf, (bf16*)gfT, gmean);
    k_metahs<<<32, 256, 0, stream>>>(meta, mw, mb, gmean, sw, sb, metag, hshift);
    k_kv<<<dim3(8, 8, 32), 256, 0, stream>>>(gfT, wkvK, wkvV, ipb, kvh, vTg);
    k_attn<<<dim3(2, 8, 32), 256, 0, stream>>>(kvh, vTg, qh, o_half, l_half);
    k_post<<<dim3(8, 32), 256, 0, stream>>>(o_half, l_half, qrs, opwT, opb, lng, lnb,
                                            metag, hshift, twT, tbv, pw1T, pb1, pw2, pb2,
                                            p0a, (bf16*)twbf, out_amp, out_ppos,
                                            out_dip, out_vol);
    k_temporal<<<dim3(32, 32), 256, 0, stream>>>(lf, twbf, logits);
    k_envelope<<<8192, 256, 0, stream>>>(logits, out_amp, out_ppos, wds, ebp, env);
}